// Round 3
// baseline (554.454 us; speedup 1.0000x reference)
//
#include <hip/hip_runtime.h>
#include <hip/hip_bf16.h>
#include <math.h>

#define NB   16
#define NTOK 577
#define CDIM 768
#define NH   12
#define HID  3072
#define RTOT (NB*NTOK)        // 9232
#define RPAD (((RTOT+127)/128)*128) // 9344
#define BH   (NB*NH)          // 192
#define QT   40               // 640/16 fragment-tiles per (b,h)
#define KF_C (CDIM/32)        // 24

typedef __attribute__((ext_vector_type(8))) short bf16x8;
typedef __attribute__((ext_vector_type(4))) float f32x4;
typedef unsigned short u16;

__device__ inline void load_lds16(const void* g, void* l) {
    __builtin_amdgcn_global_load_lds(
        (const __attribute__((address_space(1))) unsigned*)g,
        (__attribute__((address_space(3))) unsigned*)l, 16, 0, 0);
}

// fragment-blob address for element (m, c) of an [M][C] bf16 matrix packed in
// MFMA A-operand order: blob(mt, kf) is 512 u16, lane(fq*16+fr) holds 8 elems.
__device__ inline size_t blobA(int m, int c, int Kf) {
    return ((size_t)(m >> 4) * Kf + (c >> 5)) * 512 +
           (((c >> 3) & 3) * 16 + (m & 15)) * 8 + (c & 7);
}

// exp-based tanh gelu
__device__ inline float fast_gelu(float x) {
    float y = 0.7978845608f * (x + 0.044715f * x * x * x);
    float e = __expf(2.0f * y);
    float th = 1.0f - 2.0f / (e + 1.0f);
    return 0.5f * x * (1.0f + th);
}

// ---------------------------------------------------------------------------
// Weight fp32 [K][N] -> bf16 fragment blobs (B-operand: roles m->n, c->k).
// ---------------------------------------------------------------------------
__global__ __launch_bounds__(256) void wconvert_blob(
    const float* __restrict__ src, u16* __restrict__ dst, int K, int N)
{
    int n  = blockIdx.x * 256 + threadIdx.x;
    int kp = blockIdx.y;                     // k-chunk of 8
    const float* s = src + (size_t)(kp * 8) * N + n;
    __hip_bfloat16 h0 = __float2bfloat16(s[0 * N]);
    __hip_bfloat16 h1 = __float2bfloat16(s[1 * N]);
    __hip_bfloat16 h2 = __float2bfloat16(s[2 * N]);
    __hip_bfloat16 h3 = __float2bfloat16(s[3 * N]);
    __hip_bfloat16 h4 = __float2bfloat16(s[4 * N]);
    __hip_bfloat16 h5 = __float2bfloat16(s[5 * N]);
    __hip_bfloat16 h6 = __float2bfloat16(s[6 * N]);
    __hip_bfloat16 h7 = __float2bfloat16(s[7 * N]);
    ushort4 a = make_ushort4(*(u16*)&h0, *(u16*)&h1, *(u16*)&h2, *(u16*)&h3);
    ushort4 b = make_ushort4(*(u16*)&h4, *(u16*)&h5, *(u16*)&h6, *(u16*)&h7);
    u16* d = dst + ((size_t)(n >> 4) * (K >> 5) + (kp >> 2)) * 512 +
             ((kp & 3) * 16 + (n & 15)) * 8;
    *(ushort4*)(d)     = a;
    *(ushort4*)(d + 4) = b;
}

// ---------------------------------------------------------------------------
// LayerNorm -> bf16 fragment blob (Kf = 24)
// ---------------------------------------------------------------------------
__global__ __launch_bounds__(256) void ln_kernel(
    const float* __restrict__ x, const float* __restrict__ g,
    const float* __restrict__ b, u16* __restrict__ out)
{
    int row = blockIdx.x;
    const float* xr = x + (size_t)row * CDIM;
    int t = threadIdx.x;
    float v0 = xr[t], v1 = xr[t + 256], v2 = xr[t + 512];
    float s  = v0 + v1 + v2;
    float s2 = v0*v0 + v1*v1 + v2*v2;
    #pragma unroll
    for (int off = 32; off; off >>= 1) {
        s  += __shfl_xor(s, off);
        s2 += __shfl_xor(s2, off);
    }
    __shared__ float red[10];
    int wave = t >> 6, lane = t & 63;
    if (lane == 0) { red[wave] = s; red[wave + 4] = s2; }
    __syncthreads();
    if (t == 0) {
        float ts  = red[0] + red[1] + red[2] + red[3];
        float ts2 = red[4] + red[5] + red[6] + red[7];
        float mu  = ts * (1.0f / CDIM);
        float var = ts2 * (1.0f / CDIM) - mu * mu;
        red[8] = mu;
        red[9] = rsqrtf(var + 1e-5f);
    }
    __syncthreads();
    float mu = red[8], rs = red[9];
    #pragma unroll
    for (int i = 0; i < 3; ++i) {
        int c = t + i * 256;
        float v = (i == 0 ? v0 : (i == 1 ? v1 : v2));
        __hip_bfloat16 hb = __float2bfloat16((v - mu) * rs * g[c] + b[c]);
        out[blobA(row, c, KF_C)] = *(u16*)&hb;
    }
}

// ---------------------------------------------------------------------------
// 4-wave (256-thread) flatmm. Each wave computes a 64x64 tile worth of MFMA.
// Two wave layouts:
//   default      : waves = 4 consecutive m-tiles (no barriers, independent)
//   flag 32      : split-K x4 — all 4 waves on ONE (m,n) tile, each a quarter
//                  of K; LDS tree-reduce; wave 0 does bias/res/store epilogue.
// Grid: 1-D with XCD swizzle over m-units; flag16 = slab-inner order.
// flags: bit0=gelu, bit2=blob out, bit3=qkv scatter, bit4=slab-inner,
//        bit5=split-K x4.
// K-loop: depth-2 prefetch, 3-way unrolled (Kf-per-slice % 3 == 0 for all
// uses: 24,24,6,24). Tail over-reads stay inside the workspace.
// ---------------------------------------------------------------------------
template<int TM>
__global__ __launch_bounds__(256) void flat_gemm(
    const u16* __restrict__ Ab, const u16* __restrict__ Bb,
    const float* __restrict__ bias, const float* __restrict__ res,
    void* __restrict__ outv,
    u16* __restrict__ Qp, u16* __restrict__ Kp, u16* __restrict__ Vp,
    int M, int Nc, int K, int nb, int munits, int flags)
{
    __shared__ __align__(16) char smem[TM * 2048 * 4]; // 32KB: blob staging (4x8KB) / splitk reduce (24KB)
    int tid = threadIdx.x;
    int lane = tid & 63, wv = tid >> 6;
    int fr = lane & 15, fq = lane >> 4;

    int fid = blockIdx.x;
    int xcd = fid & 7, w = fid >> 3;
    int slab, n;
    if (flags & 16) {
        int nslab = (munits + 7) >> 3;
        n = w / nslab; slab = w - n * nslab;
    } else {
        slab = w / nb; n = w - slab * nb;
    }
    int mu = slab * 8 + xcd;
    if (mu >= munits) return;

    int mbtiles = (M + TM * 16 - 1) / (TM * 16);
    int splitk = flags & 32;
    int mtile, ks;
    if (splitk) { mtile = mu;          ks = wv; }
    else        { mtile = mu * 4 + wv; ks = 0;  }
    if (mtile >= mbtiles) return;      // splitk: uniform across block (mu==mtile)
    int m0 = mtile * (TM * 16), n0 = n * 64;

    int Kf = K >> 5;
    int Kfs = splitk ? (Kf >> 2) : Kf;
    size_t tstr = (size_t)Kf * 512;
    size_t koff = (size_t)ks * Kfs * 512;
    const u16* Ap = Ab + (size_t)(m0 >> 4) * tstr + koff + lane * 8;
    const u16* Bp = Bb + (size_t)(n0 >> 4) * tstr + koff + lane * 8;

    f32x4 acc[TM][4];
    #pragma unroll
    for (int i = 0; i < TM; ++i)
        #pragma unroll
        for (int j = 0; j < 4; ++j) acc[i][j] = (f32x4){0.f, 0.f, 0.f, 0.f};

#define PF_LD(Abuf, Bbuf, OFF) do {                                          \
    _Pragma("unroll")                                                        \
    for (int tm = 0; tm < TM; ++tm)                                          \
        Abuf[tm] = *(const bf16x8*)(Ap + tm * tstr + (OFF));                 \
    _Pragma("unroll")                                                        \
    for (int tn = 0; tn < 4; ++tn)                                           \
        Bbuf[tn] = *(const bf16x8*)(Bp + tn * tstr + (OFF));                 \
} while (0)

#define PF_FM(Abuf, Bbuf) do {                                               \
    _Pragma("unroll")                                                        \
    for (int tm = 0; tm < TM; ++tm)                                          \
        _Pragma("unroll")                                                    \
        for (int tn = 0; tn < 4; ++tn)                                       \
            acc[tm][tn] = __builtin_amdgcn_mfma_f32_16x16x32_bf16(           \
                Abuf[tm], Bbuf[tn], acc[tm][tn], 0, 0, 0);                   \
} while (0)

    bf16x8 A0[TM], B0[4], A1[TM], B1[4], A2[TM], B2[4];
    PF_LD(A0, B0, 0);
    PF_LD(A1, B1, 512);
    for (int kf = 0; kf < Kfs; kf += 3) {
        size_t base = (size_t)kf * 512;
        PF_LD(A2, B2, base + 1024); PF_FM(A0, B0);
        PF_LD(A0, B0, base + 1536); PF_FM(A1, B1);
        PF_LD(A1, B1, base + 2048); PF_FM(A2, B2);
    }
#undef PF_LD
#undef PF_FM

    float* outf = (float*)outv;
    u16* outblob = (u16*)outv;
    int gelu = flags & 1;
    int KfO = Nc >> 5;

    if (splitk) {
        // LDS tree-reduce: waves 1..3 publish acc in 2 chunks of 2 tm-tiles;
        // wave 0 accumulates, then owns the epilogue.
        float* red = (float*)smem;     // 3 waves x 8KB per chunk
        #pragma unroll
        for (int c = 0; c < 2; ++c) {
            if (wv != 0) {
                float* wr = red + (wv - 1) * 2048;
                #pragma unroll
                for (int tm2 = 0; tm2 < 2; ++tm2)
                    #pragma unroll
                    for (int tn = 0; tn < 4; ++tn)
                        *(f32x4*)(wr + (tm2 * 4 + tn) * 256 + lane * 4) =
                            acc[c * 2 + tm2][tn];
            }
            __syncthreads();
            if (wv == 0) {
                #pragma unroll
                for (int s = 0; s < 3; ++s)
                    #pragma unroll
                    for (int tm2 = 0; tm2 < 2; ++tm2)
                        #pragma unroll
                        for (int tn = 0; tn < 4; ++tn)
                            acc[c * 2 + tm2][tn] +=
                                *(const f32x4*)(red + s * 2048 +
                                                (tm2 * 4 + tn) * 256 + lane * 4);
            }
            if (c == 0) __syncthreads();
        }
        if (wv != 0) return;
        #pragma unroll
        for (int tm = 0; tm < TM; ++tm) {
            #pragma unroll
            for (int rg = 0; rg < 4; ++rg) {
                int gm = m0 + tm * 16 + fq * 4 + rg;
                if (gm >= M) continue;
                #pragma unroll
                for (int tn = 0; tn < 4; ++tn) {
                    int gn = n0 + tn * 16 + fr;
                    float v = acc[tm][tn][rg] + bias[gn];
                    if (res)  v += res[(size_t)gm * Nc + gn];
                    outf[(size_t)gm * Nc + gn] = v;
                }
            }
        }
        return;
    }

    if (flags & 8) {
        // qkv scatter: 64-col tile is one (sec, head), uniform per block
        int sec = n0 / CDIM;
        int h   = (n0 % CDIM) / 64;
        #pragma unroll
        for (int tm = 0; tm < TM; ++tm) {
            #pragma unroll
            for (int rg = 0; rg < 4; ++rg) {
                int gm = m0 + tm * 16 + fq * 4 + rg;
                if (gm >= M) continue;
                int b   = gm / NTOK;
                int row = gm - b * NTOK;
                int bh  = b * NH + h;
                #pragma unroll
                for (int tn = 0; tn < 4; ++tn) {
                    int d = tn * 16 + fr;
                    float v = acc[tm][tn][rg] + bias[n0 + tn * 16 + fr];
                    __hip_bfloat16 hb = __float2bfloat16(v);
                    if (sec == 0) {
                        Qp[(size_t)(bh * QT + (row >> 4)) * 1024 + (d >> 5) * 512 +
                           (((d >> 3) & 3) * 16 + (row & 15)) * 8 + (d & 7)] = *(u16*)&hb;
                    } else if (sec == 1) {
                        Kp[(size_t)(bh * QT + (row >> 4)) * 1024 + (d >> 5) * 512 +
                           (((d >> 3) & 3) * 16 + (row & 15)) * 8 + (d & 7)] = *(u16*)&hb;
                    } else {
                        Vp[((size_t)(bh * 4 + (d >> 4)) * 20 + (row >> 5)) * 512 +
                           (((row >> 3) & 3) * 16 + (d & 15)) * 8 + (row & 7)] = *(u16*)&hb;
                    }
                }
            }
        }
        return;
    }

    if (flags & 4) {
        // blob out: per-wave 8KB LDS region, wave-synchronous stage + 16B stores
        u16* sb = (u16*)smem + wv * (TM * 1024);
        #pragma unroll
        for (int tm = 0; tm < TM; ++tm)
            #pragma unroll
            for (int tn = 0; tn < 4; ++tn)
                #pragma unroll
                for (int rg = 0; rg < 4; ++rg) {
                    int cl = tn * 16 + fr;
                    float v = acc[tm][tn][rg] + bias[n0 + cl];
                    if (gelu) v = fast_gelu(v);
                    __hip_bfloat16 hb = __float2bfloat16(v);
                    sb[tm * 1024 + (cl >> 5) * 512 +
                       (((cl >> 3) & 3) * 16 + fq * 4 + rg) * 8 + (cl & 7)] = *(u16*)&hb;
                }
        #pragma unroll
        for (int tm = 0; tm < TM; ++tm) {
            u16* dst = outblob + ((size_t)((m0 >> 4) + tm) * KfO + (n0 >> 5)) * 512;
            *(bf16x8*)(dst + lane * 16)     = *(const bf16x8*)(sb + tm * 1024 + lane * 16);
            *(bf16x8*)(dst + lane * 16 + 8) = *(const bf16x8*)(sb + tm * 1024 + lane * 16 + 8);
        }
        return;
    }

    #pragma unroll
    for (int tm = 0; tm < TM; ++tm) {
        #pragma unroll
        for (int rg = 0; rg < 4; ++rg) {
            int gm = m0 + tm * 16 + fq * 4 + rg;
            if (gm >= M) continue;
            #pragma unroll
            for (int tn = 0; tn < 4; ++tn) {
                int gn = n0 + tn * 16 + fr;
                float v = acc[tm][tn][rg] + bias[gn];
                if (gelu) v = fast_gelu(v);
                if (res)  v += res[(size_t)gm * Nc + gn];
                outf[(size_t)gm * Nc + gn] = v;
            }
        }
    }
}

// ---------------------------------------------------------------------------
// MFMA flash attention; output written in fragment-blob order (proj's A).
// ---------------------------------------------------------------------------
__global__ __launch_bounds__(256) void attn_mfma(
    const u16* __restrict__ Qp, const u16* __restrict__ Kp,
    const u16* __restrict__ Vp, u16* __restrict__ outp)
{
    __shared__ __align__(16) u16 Ks[4096];
    __shared__ __align__(16) u16 Vs[4096];
    __shared__ __align__(16) u16 Ps[4 * 16 * 72];

    int bh = blockIdx.y, qc = blockIdx.x;
    int b = bh / NH, h = bh % NH;
    int t = threadIdx.x, lane = t & 63, wv = t >> 6;
    int fr = lane & 15, fq = lane >> 4;

    int mt = qc * 4 + wv;
    const u16* qbase = Qp + (size_t)(bh * QT + mt) * 1024 + lane * 8;
    bf16x8 qf0 = *(const bf16x8*)(qbase);
    bf16x8 qf1 = *(const bf16x8*)(qbase + 512);

    const u16* kg = Kp + (size_t)bh * (QT * 1024) + wv * 1024 + lane * 8;
    const u16* vg = Vp + ((size_t)(bh * 4 + wv) * 20) * 512 + lane * 8;
    u16* lK  = Ks + wv * 1024;
    u16* lV  = Vs + wv * 1024;
    u16* psw = Ps + wv * (16 * 72);

    f32x4 o[4];
    float m_r[4], l_r[4];
    #pragma unroll
    for (int i = 0; i < 4; ++i) {
        o[i] = (f32x4){0.f, 0.f, 0.f, 0.f};
        m_r[i] = -1e30f; l_r[i] = 0.f;
    }

    for (int kt = 0; kt < 10; ++kt) {
        load_lds16(kg + kt * 4096,       lK);
        load_lds16(kg + kt * 4096 + 512, lK + 512);
        load_lds16(vg + kt * 1024,       lV);
        load_lds16(vg + kt * 1024 + 512, lV + 512);
        __syncthreads();

        f32x4 sc[4];
        #pragma unroll
        for (int nt = 0; nt < 4; ++nt) {
            sc[nt] = (f32x4){0.f, 0.f, 0.f, 0.f};
            bf16x8 kf0 = *(const bf16x8*)(Ks + (nt * 2 + 0) * 512 + lane * 8);
            bf16x8 kf1 = *(const bf16x8*)(Ks + (nt * 2 + 1) * 512 + lane * 8);
            sc[nt] = __builtin_amdgcn_mfma_f32_16x16x32_bf16(qf0, kf0, sc[nt], 0, 0, 0);
            sc[nt] = __builtin_amdgcn_mfma_f32_16x16x32_bf16(qf1, kf1, sc[nt], 0, 0, 0);
        }

        int j0 = kt * 64;
        float p[4][4], rm[4];
        #pragma unroll
        for (int rg = 0; rg < 4; ++rg) rm[rg] = -1e30f;
        #pragma unroll
        for (int nt = 0; nt < 4; ++nt) {
            bool valid = (j0 + nt * 16 + fr) < NTOK;
            #pragma unroll
            for (int rg = 0; rg < 4; ++rg) {
                float sv = valid ? sc[nt][rg] * 0.125f : -1e30f;
                p[nt][rg] = sv;
                rm[rg] = fmaxf(rm[rg], sv);
            }
        }
        #pragma unroll
        for (int rg = 0; rg < 4; ++rg) {
            #pragma unroll
            for (int off = 1; off < 16; off <<= 1)
                rm[rg] = fmaxf(rm[rg], __shfl_xor(rm[rg], off));
        }
        float alpha[4], rs[4];
        #pragma unroll
        for (int rg = 0; rg < 4; ++rg) {
            float mn = fmaxf(m_r[rg], rm[rg]);
            alpha[rg] = __expf(m_r[rg] - mn);
            m_r[rg] = mn;
            rs[rg] = 0.f;
        }
        #pragma unroll
        for (int nt = 0; nt < 4; ++nt)
            #pragma unroll
            for (int rg = 0; rg < 4; ++rg) {
                float pv = __expf(p[nt][rg] - m_r[rg]);
                p[nt][rg] = pv;
                rs[rg] += pv;
            }
        #pragma unroll
        for (int rg = 0; rg < 4; ++rg) {
            #pragma unroll
            for (int off = 1; off < 16; off <<= 1)
                rs[rg] += __shfl_xor(rs[rg], off);
            l_r[rg] = l_r[rg] * alpha[rg] + rs[rg];
        }

        #pragma unroll
        for (int nt = 0; nt < 4; ++nt)
            #pragma unroll
            for (int rg = 0; rg < 4; ++rg) {
                __hip_bfloat16 hb = __float2bfloat16(p[nt][rg]);
                psw[(fq * 4 + rg) * 72 + nt * 16 + fr] = *(u16*)&hb;
            }
        #pragma unroll
        for (int dt = 0; dt < 4; ++dt)
            #pragma unroll
            for (int rg = 0; rg < 4; ++rg)
                o[dt][rg] *= alpha[rg];

        bf16x8 pf0 = *(const bf16x8*)(psw + fr * 72 + fq * 8);
        bf16x8 pf1 = *(const bf16x8*)(psw + fr * 72 + 32 + fq * 8);
        #pragma unroll
        for (int dt = 0; dt < 4; ++dt) {
            bf16x8 bv0 = *(const bf16x8*)(Vs + (dt * 2 + 0) * 512 + lane * 8);
            bf16x8 bv1 = *(const bf16x8*)(Vs + (dt * 2 + 1) * 512 + lane * 8);
            o[dt] = __builtin_amdgcn_mfma_f32_16x16x32_bf16(pf0, bv0, o[dt], 0, 0, 0);
            o[dt] = __builtin_amdgcn_mfma_f32_16x16x32_bf16(pf1, bv1, o[dt], 0, 0, 0);
        }
        __syncthreads();
    }

    #pragma unroll
    for (int rg = 0; rg < 4; ++rg) {
        int row = qc * 64 + wv * 16 + fq * 4 + rg;
        if (row < NTOK) {
            float rl = 1.0f / l_r[rg];
            int grow = b * NTOK + row;
            #pragma unroll
            for (int dt = 0; dt < 4; ++dt) {
                __hip_bfloat16 hb = __float2bfloat16(o[dt][rg] * rl);
                outp[blobA(grow, h * 64 + dt * 16 + fr, KF_C)] = *(u16*)&hb;
            }
        }
    }
}

// ---------------------------------------------------------------------------
static inline int swz_grid(int nb, int munits) { return nb * (((munits + 7) / 8) * 8); }

extern "C" void kernel_launch(void* const* d_in, const int* in_sizes, int n_in,
                              void* d_out, int out_size, void* d_ws, size_t ws_size,
                              hipStream_t stream)
{
    const float* x      = (const float*)d_in[0];
    const float* ln1_g  = (const float*)d_in[1];
    const float* ln1_b  = (const float*)d_in[2];
    const float* w_qkv  = (const float*)d_in[3];
    const float* b_qkv  = (const float*)d_in[4];
    const float* w_proj = (const float*)d_in[5];
    const float* b_proj = (const float*)d_in[6];
    const float* ln2_g  = (const float*)d_in[7];
    const float* ln2_b  = (const float*)d_in[8];
    const float* w_fc1  = (const float*)d_in[9];
    const float* b_fc1  = (const float*)d_in[10];
    const float* w_fc2  = (const float*)d_in[11];
    const float* b_fc2  = (const float*)d_in[12];
    float* out = (float*)d_out;

    char* w = (char*)d_ws;
    u16* Bqkv = (u16*)w; w += (size_t)3*CDIM*CDIM*2;
    u16* Bproj= (u16*)w; w += (size_t)CDIM*CDIM*2;
    u16* Bfc1 = (u16*)w; w += (size_t)HID*CDIM*2;
    u16* Bfc2 = (u16*)w; w += (size_t)CDIM*HID*2;
    u16* hA   = (u16*)w; w += (size_t)RPAD*CDIM*2;   // blob activations (768)
    u16* h3A  = (u16*)w; w += (size_t)RPAD*HID*2;    // blob activations (3072)
    u16* Qp   = (u16*)w; w += (size_t)BH*QT*1024*2;
    u16* Kp   = (u16*)w; w += (size_t)BH*QT*1024*2;
    u16* Vp   = (u16*)w; w += (size_t)BH*4*20*512*2;

    int mt = (RTOT + 63) / 64;     // 145 wave-tiles (TM=4)
    int mg = (mt + 3) / 4;         // 37 4-tile m-groups

    // 0. weights -> fragment blobs
    wconvert_blob<<<dim3(3*CDIM/256, CDIM/8), 256, 0, stream>>>(w_qkv,  Bqkv, CDIM, 3*CDIM);
    wconvert_blob<<<dim3(CDIM/256,   CDIM/8), 256, 0, stream>>>(w_proj, Bproj, CDIM, CDIM);
    wconvert_blob<<<dim3(HID/256,    CDIM/8), 256, 0, stream>>>(w_fc1,  Bfc1, CDIM, HID);
    wconvert_blob<<<dim3(CDIM/256,   HID/8),  256, 0, stream>>>(w_fc2,  Bfc2, HID, CDIM);

    // 1. hA = LN1(x)  (blob)
    ln_kernel<<<RTOT, 256, 0, stream>>>(x, ln1_g, ln1_b, hA);
    // 2. qkv GEMM -> Q/K/V blobs  (4 m-tiles/block, slab-inner)
    flat_gemm<4><<<swz_grid(3*CDIM/64, mg), 256, 0, stream>>>(
        hA, Bqkv, b_qkv, nullptr, nullptr, Qp, Kp, Vp,
        RTOT, 3*CDIM, CDIM, 3*CDIM/64, mg, 8 | 16);
    // 3. attention -> hA (blob)
    attn_mfma<<<dim3(10, BH), 256, 0, stream>>>(Qp, Kp, Vp, hA);
    // 4. x1 = x + hA @ Bproj^T + b_proj -> d_out (fp32, split-K x4)
    flat_gemm<4><<<swz_grid(CDIM/64, mt), 256, 0, stream>>>(
        hA, Bproj, b_proj, x, out, nullptr, nullptr, nullptr,
        RTOT, CDIM, CDIM, CDIM/64, mt, 32);
    // 5. hA = LN2(x1)  (blob)
    ln_kernel<<<RTOT, 256, 0, stream>>>(out, ln2_g, ln2_b, hA);
    // 6. h3A = gelu(hA @ Bfc1^T + b_fc1)  (blob out, 4 m-tiles/block, slab-inner)
    flat_gemm<4><<<swz_grid(HID/64, mg), 256, 0, stream>>>(
        hA, Bfc1, b_fc1, nullptr, h3A, nullptr, nullptr, nullptr,
        RTOT, HID, CDIM, HID/64, mg, 1 | 4 | 16);
    // 7. out = x1 + h3A @ Bfc2^T + b_fc2  (fp32, split-K x4, res==out same-thread)
    flat_gemm<4><<<swz_grid(CDIM/64, mt), 256, 0, stream>>>(
        h3A, Bfc2, b_fc2, out, out, nullptr, nullptr, nullptr,
        RTOT, CDIM, HID, CDIM/64, mt, 32);
}

// Round 4
// 480.113 us; speedup vs baseline: 1.1548x; 1.1548x over previous
//
#include <hip/hip_runtime.h>
#include <hip/hip_bf16.h>
#include <math.h>

#define NB   16
#define NTOK 577
#define CDIM 768
#define NH   12
#define HID  3072
#define RTOT (NB*NTOK)        // 9232
#define RPAD (((RTOT+127)/128)*128) // 9344
#define BH   (NB*NH)          // 192
#define QT   40               // 640/16 fragment-tiles per (b,h)
#define KF_C (CDIM/32)        // 24

typedef __attribute__((ext_vector_type(8))) short bf16x8;
typedef __attribute__((ext_vector_type(4))) float f32x4;
typedef unsigned short u16;

__device__ inline void load_lds16(const void* g, void* l) {
    __builtin_amdgcn_global_load_lds(
        (const __attribute__((address_space(1))) unsigned*)g,
        (__attribute__((address_space(3))) unsigned*)l, 16, 0, 0);
}

// fragment-blob address for element (m, c) of an [M][C] bf16 matrix packed in
// MFMA A-operand order: blob(mt, kf) is 512 u16, lane(fq*16+fr) holds 8 elems.
__device__ inline size_t blobA(int m, int c, int Kf) {
    return ((size_t)(m >> 4) * Kf + (c >> 5)) * 512 +
           (((c >> 3) & 3) * 16 + (m & 15)) * 8 + (c & 7);
}

// exp-based tanh gelu
__device__ inline float fast_gelu(float x) {
    float y = 0.7978845608f * (x + 0.044715f * x * x * x);
    float e = __expf(2.0f * y);
    float th = 1.0f - 2.0f / (e + 1.0f);
    return 0.5f * x * (1.0f + th);
}

// ---------------------------------------------------------------------------
// Weight fp32 [K][N] -> bf16 fragment blobs (B-operand: roles m->n, c->k).
// ---------------------------------------------------------------------------
__global__ __launch_bounds__(256) void wconvert_blob(
    const float* __restrict__ src, u16* __restrict__ dst, int K, int N)
{
    int n  = blockIdx.x * 256 + threadIdx.x;
    int kp = blockIdx.y;                     // k-chunk of 8
    const float* s = src + (size_t)(kp * 8) * N + n;
    __hip_bfloat16 h0 = __float2bfloat16(s[0 * N]);
    __hip_bfloat16 h1 = __float2bfloat16(s[1 * N]);
    __hip_bfloat16 h2 = __float2bfloat16(s[2 * N]);
    __hip_bfloat16 h3 = __float2bfloat16(s[3 * N]);
    __hip_bfloat16 h4 = __float2bfloat16(s[4 * N]);
    __hip_bfloat16 h5 = __float2bfloat16(s[5 * N]);
    __hip_bfloat16 h6 = __float2bfloat16(s[6 * N]);
    __hip_bfloat16 h7 = __float2bfloat16(s[7 * N]);
    ushort4 a = make_ushort4(*(u16*)&h0, *(u16*)&h1, *(u16*)&h2, *(u16*)&h3);
    ushort4 b = make_ushort4(*(u16*)&h4, *(u16*)&h5, *(u16*)&h6, *(u16*)&h7);
    u16* d = dst + ((size_t)(n >> 4) * (K >> 5) + (kp >> 2)) * 512 +
             ((kp & 3) * 16 + (n & 15)) * 8;
    *(ushort4*)(d)     = a;
    *(ushort4*)(d + 4) = b;
}

// ---------------------------------------------------------------------------
// LayerNorm -> bf16 fragment blob (Kf = 24)
// ---------------------------------------------------------------------------
__global__ __launch_bounds__(256) void ln_kernel(
    const float* __restrict__ x, const float* __restrict__ g,
    const float* __restrict__ b, u16* __restrict__ out)
{
    int row = blockIdx.x;
    const float* xr = x + (size_t)row * CDIM;
    int t = threadIdx.x;
    float v0 = xr[t], v1 = xr[t + 256], v2 = xr[t + 512];
    float s  = v0 + v1 + v2;
    float s2 = v0*v0 + v1*v1 + v2*v2;
    #pragma unroll
    for (int off = 32; off; off >>= 1) {
        s  += __shfl_xor(s, off);
        s2 += __shfl_xor(s2, off);
    }
    __shared__ float red[10];
    int wave = t >> 6, lane = t & 63;
    if (lane == 0) { red[wave] = s; red[wave + 4] = s2; }
    __syncthreads();
    if (t == 0) {
        float ts  = red[0] + red[1] + red[2] + red[3];
        float ts2 = red[4] + red[5] + red[6] + red[7];
        float mu  = ts * (1.0f / CDIM);
        float var = ts2 * (1.0f / CDIM) - mu * mu;
        red[8] = mu;
        red[9] = rsqrtf(var + 1e-5f);
    }
    __syncthreads();
    float mu = red[8], rs = red[9];
    #pragma unroll
    for (int i = 0; i < 3; ++i) {
        int c = t + i * 256;
        float v = (i == 0 ? v0 : (i == 1 ? v1 : v2));
        __hip_bfloat16 hb = __float2bfloat16((v - mu) * rs * g[c] + b[c]);
        out[blobA(row, c, KF_C)] = *(u16*)&hb;
    }
}

// ---------------------------------------------------------------------------
// LDS-staged 4-wave GEMM (m97 structure). Block tile = (MBL*16) x (NBL*16),
// BK = 32 (one blob column per step). 2x2 wave grid: wave (wm=wv>>1, wn=wv&1)
// owns MBL/2 m-blobs x NBL/2 n-blobs. Per K-step: each wave DMAs
// (MBL+NBL)/4 next-step blobs via global_load_lds (1 KB each, wave-uniform
// LDS dest + lane*16B — blob format IS the linear order), ds_read_b128 its
// fragments from the current buffer, MFMAs, one __syncthreads (drains vmcnt,
// so the prefetched buffer is ready at the next iteration).
// FLAGS: 1=gelu, 4=blob out, 8=qkv scatter, else fp32 out (+res).
// ---------------------------------------------------------------------------
template<int MBL, int NBL, int FLAGS>
__global__ __launch_bounds__(256) void tile_gemm(
    const u16* __restrict__ Ab, const u16* __restrict__ Bb,
    const float* __restrict__ bias, const float* __restrict__ res,
    void* __restrict__ outv,
    u16* __restrict__ Qp, u16* __restrict__ Kp, u16* __restrict__ Vp,
    int M, int Nc, int K)
{
    constexpr int NST  = (MBL + NBL) / 4;   // DMA blobs per wave per step
    constexpr int BUFU = (MBL + NBL) * 512; // u16 per buffer
    constexpr int MH2  = MBL / 2, NW2 = NBL / 2;
    __shared__ __align__(16) u16 smem[2 * BUFU];

    int tid = threadIdx.x, lane = tid & 63, wv = tid >> 6;
    int fr = lane & 15, fq = lane >> 4;
    int wm = wv >> 1, wn = wv & 1;

    int m0 = blockIdx.y * (MBL * 16), n0 = blockIdx.x * (NBL * 16);
    int Kf = K >> 5;
    size_t tstr = (size_t)Kf * 512;

    // staging pointers: blob bi = wv + i*4; [0,MBL)=A-blobs, rest B-blobs
    const u16* gp[NST];
    u16* ldst[NST];
    #pragma unroll
    for (int i = 0; i < NST; ++i) {
        int bi = wv + i * 4;
        gp[i] = (bi < MBL)
            ? Ab + ((size_t)(m0 >> 4) + bi) * tstr + lane * 8
            : Bb + ((size_t)(n0 >> 4) + (bi - MBL)) * tstr + lane * 8;
        ldst[i] = smem + bi * 512;
    }

    f32x4 acc[MH2][NW2];
    #pragma unroll
    for (int mi = 0; mi < MH2; ++mi)
        #pragma unroll
        for (int ni = 0; ni < NW2; ++ni) acc[mi][ni] = (f32x4){0.f, 0.f, 0.f, 0.f};

    #pragma unroll
    for (int i = 0; i < NST; ++i) load_lds16(gp[i], ldst[i]);
    __syncthreads();

    for (int t = 0; t < Kf; ++t) {
        int cur = (t & 1) * BUFU, nxt = ((t + 1) & 1) * BUFU;
        if (t + 1 < Kf) {
            #pragma unroll
            for (int i = 0; i < NST; ++i)
                load_lds16(gp[i] + (size_t)(t + 1) * 512, ldst[i] + nxt);
        }
        bf16x8 a[MH2], bfr[NW2];
        #pragma unroll
        for (int mi = 0; mi < MH2; ++mi)
            a[mi] = *(const bf16x8*)(smem + cur + (wm * MH2 + mi) * 512 + lane * 8);
        #pragma unroll
        for (int ni = 0; ni < NW2; ++ni)
            bfr[ni] = *(const bf16x8*)(smem + cur + (MBL + wn * NW2 + ni) * 512 + lane * 8);
        #pragma unroll
        for (int mi = 0; mi < MH2; ++mi)
            #pragma unroll
            for (int ni = 0; ni < NW2; ++ni)
                acc[mi][ni] = __builtin_amdgcn_mfma_f32_16x16x32_bf16(
                    a[mi], bfr[ni], acc[mi][ni], 0, 0, 0);
        __syncthreads();
    }

    int m0w = m0 + wm * (MH2 * 16);
    int n0w = n0 + wn * (NW2 * 16);
    float* outf = (float*)outv;
    u16* outblob = (u16*)outv;

    if constexpr ((FLAGS & 8) != 0) {
        // qkv scatter: wave's 64-col span is one (sec, head), uniform per wave
        int sec = n0w / CDIM;
        int h   = (n0w % CDIM) / 64;
        #pragma unroll
        for (int mi = 0; mi < MH2; ++mi) {
            #pragma unroll
            for (int rg = 0; rg < 4; ++rg) {
                int gm = m0w + mi * 16 + fq * 4 + rg;
                if (gm >= M) continue;
                int b   = gm / NTOK;
                int row = gm - b * NTOK;
                int bh  = b * NH + h;
                #pragma unroll
                for (int ni = 0; ni < NW2; ++ni) {
                    int d = ni * 16 + fr;
                    float v = acc[mi][ni][rg] + bias[n0w + d];
                    __hip_bfloat16 hb = __float2bfloat16(v);
                    if (sec == 0) {
                        Qp[(size_t)(bh * QT + (row >> 4)) * 1024 + (d >> 5) * 512 +
                           (((d >> 3) & 3) * 16 + (row & 15)) * 8 + (d & 7)] = *(u16*)&hb;
                    } else if (sec == 1) {
                        Kp[(size_t)(bh * QT + (row >> 4)) * 1024 + (d >> 5) * 512 +
                           (((d >> 3) & 3) * 16 + (row & 15)) * 8 + (d & 7)] = *(u16*)&hb;
                    } else {
                        Vp[((size_t)(bh * 4 + (d >> 4)) * 20 + (row >> 5)) * 512 +
                           (((row >> 3) & 3) * 16 + (d & 15)) * 8 + (row & 7)] = *(u16*)&hb;
                    }
                }
            }
        }
        return;
    }

    if constexpr ((FLAGS & 4) != 0) {
        // blob out: per-wave private 2KB LDS staging per m-blob (wave-sync:
        // same wave writes then reads, program order), then linear 16B stores.
        u16* sb = smem + wv * 1024;
        int KfO = Nc >> 5;
        #pragma unroll
        for (int mi = 0; mi < MH2; ++mi) {
            #pragma unroll
            for (int ni = 0; ni < NW2; ++ni)
                #pragma unroll
                for (int rg = 0; rg < 4; ++rg) {
                    int cl = ni * 16 + fr;
                    float v = acc[mi][ni][rg] + bias[n0w + cl];
                    if (FLAGS & 1) v = fast_gelu(v);
                    __hip_bfloat16 hb = __float2bfloat16(v);
                    sb[(cl >> 5) * 512 +
                       (((cl >> 3) & 3) * 16 + fq * 4 + rg) * 8 + (cl & 7)] = *(u16*)&hb;
                }
            u16* dst = outblob + ((size_t)((m0w >> 4) + mi) * KfO + (n0w >> 5)) * 512;
            *(bf16x8*)(dst + lane * 16)     = *(const bf16x8*)(sb + lane * 16);
            *(bf16x8*)(dst + lane * 16 + 8) = *(const bf16x8*)(sb + lane * 16 + 8);
        }
        return;
    }

    #pragma unroll
    for (int mi = 0; mi < MH2; ++mi) {
        #pragma unroll
        for (int rg = 0; rg < 4; ++rg) {
            int gm = m0w + mi * 16 + fq * 4 + rg;
            if (gm >= M) continue;
            #pragma unroll
            for (int ni = 0; ni < NW2; ++ni) {
                int gn = n0w + ni * 16 + fr;
                float v = acc[mi][ni][rg] + bias[gn];
                if (res) v += res[(size_t)gm * Nc + gn];
                outf[(size_t)gm * Nc + gn] = v;
            }
        }
    }
}

// ---------------------------------------------------------------------------
// MFMA flash attention; output written in fragment-blob order (proj's A).
// ---------------------------------------------------------------------------
__global__ __launch_bounds__(256) void attn_mfma(
    const u16* __restrict__ Qp, const u16* __restrict__ Kp,
    const u16* __restrict__ Vp, u16* __restrict__ outp)
{
    __shared__ __align__(16) u16 Ks[4096];
    __shared__ __align__(16) u16 Vs[4096];
    __shared__ __align__(16) u16 Ps[4 * 16 * 72];

    int bh = blockIdx.y, qc = blockIdx.x;
    int b = bh / NH, h = bh % NH;
    int t = threadIdx.x, lane = t & 63, wv = t >> 6;
    int fr = lane & 15, fq = lane >> 4;

    int mt = qc * 4 + wv;
    const u16* qbase = Qp + (size_t)(bh * QT + mt) * 1024 + lane * 8;
    bf16x8 qf0 = *(const bf16x8*)(qbase);
    bf16x8 qf1 = *(const bf16x8*)(qbase + 512);

    const u16* kg = Kp + (size_t)bh * (QT * 1024) + wv * 1024 + lane * 8;
    const u16* vg = Vp + ((size_t)(bh * 4 + wv) * 20) * 512 + lane * 8;
    u16* lK  = Ks + wv * 1024;
    u16* lV  = Vs + wv * 1024;
    u16* psw = Ps + wv * (16 * 72);

    f32x4 o[4];
    float m_r[4], l_r[4];
    #pragma unroll
    for (int i = 0; i < 4; ++i) {
        o[i] = (f32x4){0.f, 0.f, 0.f, 0.f};
        m_r[i] = -1e30f; l_r[i] = 0.f;
    }

    for (int kt = 0; kt < 10; ++kt) {
        load_lds16(kg + kt * 4096,       lK);
        load_lds16(kg + kt * 4096 + 512, lK + 512);
        load_lds16(vg + kt * 1024,       lV);
        load_lds16(vg + kt * 1024 + 512, lV + 512);
        __syncthreads();

        f32x4 sc[4];
        #pragma unroll
        for (int nt = 0; nt < 4; ++nt) {
            sc[nt] = (f32x4){0.f, 0.f, 0.f, 0.f};
            bf16x8 kf0 = *(const bf16x8*)(Ks + (nt * 2 + 0) * 512 + lane * 8);
            bf16x8 kf1 = *(const bf16x8*)(Ks + (nt * 2 + 1) * 512 + lane * 8);
            sc[nt] = __builtin_amdgcn_mfma_f32_16x16x32_bf16(qf0, kf0, sc[nt], 0, 0, 0);
            sc[nt] = __builtin_amdgcn_mfma_f32_16x16x32_bf16(qf1, kf1, sc[nt], 0, 0, 0);
        }

        int j0 = kt * 64;
        float p[4][4], rm[4];
        #pragma unroll
        for (int rg = 0; rg < 4; ++rg) rm[rg] = -1e30f;
        #pragma unroll
        for (int nt = 0; nt < 4; ++nt) {
            bool valid = (j0 + nt * 16 + fr) < NTOK;
            #pragma unroll
            for (int rg = 0; rg < 4; ++rg) {
                float sv = valid ? sc[nt][rg] * 0.125f : -1e30f;
                p[nt][rg] = sv;
                rm[rg] = fmaxf(rm[rg], sv);
            }
        }
        #pragma unroll
        for (int rg = 0; rg < 4; ++rg) {
            #pragma unroll
            for (int off = 1; off < 16; off <<= 1)
                rm[rg] = fmaxf(rm[rg], __shfl_xor(rm[rg], off));
        }
        float alpha[4], rs[4];
        #pragma unroll
        for (int rg = 0; rg < 4; ++rg) {
            float mn = fmaxf(m_r[rg], rm[rg]);
            alpha[rg] = __expf(m_r[rg] - mn);
            m_r[rg] = mn;
            rs[rg] = 0.f;
        }
        #pragma unroll
        for (int nt = 0; nt < 4; ++nt)
            #pragma unroll
            for (int rg = 0; rg < 4; ++rg) {
                float pv = __expf(p[nt][rg] - m_r[rg]);
                p[nt][rg] = pv;
                rs[rg] += pv;
            }
        #pragma unroll
        for (int rg = 0; rg < 4; ++rg) {
            #pragma unroll
            for (int off = 1; off < 16; off <<= 1)
                rs[rg] += __shfl_xor(rs[rg], off);
            l_r[rg] = l_r[rg] * alpha[rg] + rs[rg];
        }

        #pragma unroll
        for (int nt = 0; nt < 4; ++nt)
            #pragma unroll
            for (int rg = 0; rg < 4; ++rg) {
                __hip_bfloat16 hb = __float2bfloat16(p[nt][rg]);
                psw[(fq * 4 + rg) * 72 + nt * 16 + fr] = *(u16*)&hb;
            }
        #pragma unroll
        for (int dt = 0; dt < 4; ++dt)
            #pragma unroll
            for (int rg = 0; rg < 4; ++rg)
                o[dt][rg] *= alpha[rg];

        bf16x8 pf0 = *(const bf16x8*)(psw + fr * 72 + fq * 8);
        bf16x8 pf1 = *(const bf16x8*)(psw + fr * 72 + 32 + fq * 8);
        #pragma unroll
        for (int dt = 0; dt < 4; ++dt) {
            bf16x8 bv0 = *(const bf16x8*)(Vs + (dt * 2 + 0) * 512 + lane * 8);
            bf16x8 bv1 = *(const bf16x8*)(Vs + (dt * 2 + 1) * 512 + lane * 8);
            o[dt] = __builtin_amdgcn_mfma_f32_16x16x32_bf16(pf0, bv0, o[dt], 0, 0, 0);
            o[dt] = __builtin_amdgcn_mfma_f32_16x16x32_bf16(pf1, bv1, o[dt], 0, 0, 0);
        }
        __syncthreads();
    }

    #pragma unroll
    for (int rg = 0; rg < 4; ++rg) {
        int row = qc * 64 + wv * 16 + fq * 4 + rg;
        if (row < NTOK) {
            float rl = 1.0f / l_r[rg];
            int grow = b * NTOK + row;
            #pragma unroll
            for (int dt = 0; dt < 4; ++dt) {
                __hip_bfloat16 hb = __float2bfloat16(o[dt][rg] * rl);
                outp[blobA(grow, h * 64 + dt * 16 + fr, KF_C)] = *(u16*)&hb;
            }
        }
    }
}

// ---------------------------------------------------------------------------
extern "C" void kernel_launch(void* const* d_in, const int* in_sizes, int n_in,
                              void* d_out, int out_size, void* d_ws, size_t ws_size,
                              hipStream_t stream)
{
    const float* x      = (const float*)d_in[0];
    const float* ln1_g  = (const float*)d_in[1];
    const float* ln1_b  = (const float*)d_in[2];
    const float* w_qkv  = (const float*)d_in[3];
    const float* b_qkv  = (const float*)d_in[4];
    const float* w_proj = (const float*)d_in[5];
    const float* b_proj = (const float*)d_in[6];
    const float* ln2_g  = (const float*)d_in[7];
    const float* ln2_b  = (const float*)d_in[8];
    const float* w_fc1  = (const float*)d_in[9];
    const float* b_fc1  = (const float*)d_in[10];
    const float* w_fc2  = (const float*)d_in[11];
    const float* b_fc2  = (const float*)d_in[12];
    float* out = (float*)d_out;

    char* w = (char*)d_ws;
    u16* Bqkv = (u16*)w; w += (size_t)3*CDIM*CDIM*2;
    u16* Bproj= (u16*)w; w += (size_t)CDIM*CDIM*2;
    u16* Bfc1 = (u16*)w; w += (size_t)HID*CDIM*2;
    u16* Bfc2 = (u16*)w; w += (size_t)CDIM*HID*2;
    u16* hA   = (u16*)w; w += (size_t)RPAD*CDIM*2;   // blob activations (768)
    u16* h3A  = (u16*)w; w += (size_t)RPAD*HID*2;    // blob activations (3072)
    u16* Qp   = (u16*)w; w += (size_t)BH*QT*1024*2;
    u16* Kp   = (u16*)w; w += (size_t)BH*QT*1024*2;
    u16* Vp   = (u16*)w; w += (size_t)BH*4*20*512*2;

    int mt128 = (RTOT + 127) / 128;   // 73  (73*128 = 9344 = RPAD: reads in-bounds)
    int mt64  = (RTOT + 63) / 64;     // 145

    // 0. weights -> fragment blobs
    wconvert_blob<<<dim3(3*CDIM/256, CDIM/8), 256, 0, stream>>>(w_qkv,  Bqkv, CDIM, 3*CDIM);
    wconvert_blob<<<dim3(CDIM/256,   CDIM/8), 256, 0, stream>>>(w_proj, Bproj, CDIM, CDIM);
    wconvert_blob<<<dim3(HID/256,    CDIM/8), 256, 0, stream>>>(w_fc1,  Bfc1, CDIM, HID);
    wconvert_blob<<<dim3(CDIM/256,   HID/8),  256, 0, stream>>>(w_fc2,  Bfc2, HID, CDIM);

    // 1. hA = LN1(x)  (blob)
    ln_kernel<<<RTOT, 256, 0, stream>>>(x, ln1_g, ln1_b, hA);
    // 2. qkv GEMM -> Q/K/V blobs  (128x128 tiles, 18x73 = 1314 blocks)
    tile_gemm<8, 8, 8><<<dim3(3*CDIM/128, mt128), 256, 0, stream>>>(
        hA, Bqkv, b_qkv, nullptr, nullptr, Qp, Kp, Vp, RTOT, 3*CDIM, CDIM);
    // 3. attention -> hA (blob)
    attn_mfma<<<dim3(10, BH), 256, 0, stream>>>(Qp, Kp, Vp, hA);
    // 4. x1 = x + hA @ Bproj^T + b_proj -> d_out (fp32; 64x128 tiles, 6x145)
    tile_gemm<4, 8, 0><<<dim3(CDIM/128, mt64), 256, 0, stream>>>(
        hA, Bproj, b_proj, x, out, nullptr, nullptr, nullptr, RTOT, CDIM, CDIM);
    // 5. hA = LN2(x1)  (blob)
    ln_kernel<<<RTOT, 256, 0, stream>>>(out, ln2_g, ln2_b, hA);
    // 6. h3A = gelu(hA @ Bfc1^T + b_fc1)  (blob out; 128x128 tiles, 24x73)
    tile_gemm<8, 8, 5><<<dim3(HID/128, mt128), 256, 0, stream>>>(
        hA, Bfc1, b_fc1, nullptr, h3A, nullptr, nullptr, nullptr, RTOT, HID, CDIM);
    // 7. out = x1 + h3A @ Bfc2^T + b_fc2  (fp32; 64x128 tiles, 6x145)
    tile_gemm<4, 8, 0><<<dim3(CDIM/128, mt64), 256, 0, stream>>>(
        h3A, Bfc2, b_fc2, out, out, nullptr, nullptr, nullptr, RTOT, CDIM, HID);
}

// Round 5
// 465.429 us; speedup vs baseline: 1.1913x; 1.0316x over previous
//
#include <hip/hip_runtime.h>
#include <hip/hip_bf16.h>
#include <math.h>

#define NB   16
#define NTOK 577
#define CDIM 768
#define NH   12
#define HID  3072
#define RTOT (NB*NTOK)        // 9232
#define RPAD (((RTOT+127)/128)*128) // 9344
#define BH   (NB*NH)          // 192
#define QT   40               // 640/16 fragment-tiles per (b,h)
#define KF_C (CDIM/32)        // 24

typedef __attribute__((ext_vector_type(8))) short bf16x8;
typedef __attribute__((ext_vector_type(4))) float f32x4;
typedef unsigned short u16;

__device__ inline void load_lds16(const void* g, void* l) {
    __builtin_amdgcn_global_load_lds(
        (const __attribute__((address_space(1))) unsigned*)g,
        (__attribute__((address_space(3))) unsigned*)l, 16, 0, 0);
}

// fragment-blob address for element (m, c) of an [M][C] bf16 matrix packed in
// MFMA A-operand order: blob(mt, kf) is 512 u16, lane(fq*16+fr) holds 8 elems.
__device__ inline size_t blobA(int m, int c, int Kf) {
    return ((size_t)(m >> 4) * Kf + (c >> 5)) * 512 +
           (((c >> 3) & 3) * 16 + (m & 15)) * 8 + (c & 7);
}

// exp-based tanh gelu
__device__ inline float fast_gelu(float x) {
    float y = 0.7978845608f * (x + 0.044715f * x * x * x);
    float e = __expf(2.0f * y);
    float th = 1.0f - 2.0f / (e + 1.0f);
    return 0.5f * x * (1.0f + th);
}

// ---------------------------------------------------------------------------
// Weight fp32 [K][N] -> bf16 fragment blobs (B-operand: roles m->n, c->k).
// ---------------------------------------------------------------------------
__global__ __launch_bounds__(256) void wconvert_blob(
    const float* __restrict__ src, u16* __restrict__ dst, int K, int N)
{
    int n  = blockIdx.x * 256 + threadIdx.x;
    int kp = blockIdx.y;                     // k-chunk of 8
    const float* s = src + (size_t)(kp * 8) * N + n;
    __hip_bfloat16 h0 = __float2bfloat16(s[0 * N]);
    __hip_bfloat16 h1 = __float2bfloat16(s[1 * N]);
    __hip_bfloat16 h2 = __float2bfloat16(s[2 * N]);
    __hip_bfloat16 h3 = __float2bfloat16(s[3 * N]);
    __hip_bfloat16 h4 = __float2bfloat16(s[4 * N]);
    __hip_bfloat16 h5 = __float2bfloat16(s[5 * N]);
    __hip_bfloat16 h6 = __float2bfloat16(s[6 * N]);
    __hip_bfloat16 h7 = __float2bfloat16(s[7 * N]);
    ushort4 a = make_ushort4(*(u16*)&h0, *(u16*)&h1, *(u16*)&h2, *(u16*)&h3);
    ushort4 b = make_ushort4(*(u16*)&h4, *(u16*)&h5, *(u16*)&h6, *(u16*)&h7);
    u16* d = dst + ((size_t)(n >> 4) * (K >> 5) + (kp >> 2)) * 512 +
             ((kp & 3) * 16 + (n & 15)) * 8;
    *(ushort4*)(d)     = a;
    *(ushort4*)(d + 4) = b;
}

// ---------------------------------------------------------------------------
// LayerNorm -> bf16 fragment blob (Kf = 24)
// ---------------------------------------------------------------------------
__global__ __launch_bounds__(256) void ln_kernel(
    const float* __restrict__ x, const float* __restrict__ g,
    const float* __restrict__ b, u16* __restrict__ out)
{
    int row = blockIdx.x;
    const float* xr = x + (size_t)row * CDIM;
    int t = threadIdx.x;
    float v0 = xr[t], v1 = xr[t + 256], v2 = xr[t + 512];
    float s  = v0 + v1 + v2;
    float s2 = v0*v0 + v1*v1 + v2*v2;
    #pragma unroll
    for (int off = 32; off; off >>= 1) {
        s  += __shfl_xor(s, off);
        s2 += __shfl_xor(s2, off);
    }
    __shared__ float red[10];
    int wave = t >> 6, lane = t & 63;
    if (lane == 0) { red[wave] = s; red[wave + 4] = s2; }
    __syncthreads();
    if (t == 0) {
        float ts  = red[0] + red[1] + red[2] + red[3];
        float ts2 = red[4] + red[5] + red[6] + red[7];
        float mu  = ts * (1.0f / CDIM);
        float var = ts2 * (1.0f / CDIM) - mu * mu;
        red[8] = mu;
        red[9] = rsqrtf(var + 1e-5f);
    }
    __syncthreads();
    float mu = red[8], rs = red[9];
    #pragma unroll
    for (int i = 0; i < 3; ++i) {
        int c = t + i * 256;
        float v = (i == 0 ? v0 : (i == 1 ? v1 : v2));
        __hip_bfloat16 hb = __float2bfloat16((v - mu) * rs * g[c] + b[c]);
        out[blobA(row, c, KF_C)] = *(u16*)&hb;
    }
}

// ---------------------------------------------------------------------------
// LDS-staged 4-wave GEMM (m97 structure) with XCD-slab swizzle.
// Block tile = (MBL*16) x (NBL*16), BK = 32 (one blob column per step).
// 1-D grid: xcd = fid&7 picks the m-slab residue; within an XCD the n-index
// is the INNER loop so one A-panel stays hot in that XCD's L2 while the
// B-strips sweep (R2-proven: brings FETCH to ~compulsory).
// 2x2 wave grid: wave (wm, wn) owns MBL/2 x NBL/2 blobs. Per K-step: each
// wave DMAs (MBL+NBL)/4 next-step blobs via global_load_lds (wave-uniform
// dest + lane*16B: blob format IS the linear order), ds_read_b128 current
// fragments, MFMAs, one __syncthreads.
// FLAGS: 1=gelu, 4=blob out, 8=qkv scatter, else fp32 out (+res).
// ---------------------------------------------------------------------------
template<int MBL, int NBL, int FLAGS>
__global__ __launch_bounds__(256) void tile_gemm(
    const u16* __restrict__ Ab, const u16* __restrict__ Bb,
    const float* __restrict__ bias, const float* __restrict__ res,
    void* __restrict__ outv,
    u16* __restrict__ Qp, u16* __restrict__ Kp, u16* __restrict__ Vp,
    int M, int Nc, int K, int nb, int mtiles)
{
    constexpr int NST  = (MBL + NBL) / 4;   // DMA blobs per wave per step
    constexpr int BUFU = (MBL + NBL) * 512; // u16 per buffer
    constexpr int MH2  = MBL / 2, NW2 = NBL / 2;
    __shared__ __align__(16) u16 smem[2 * BUFU];

    int tid = threadIdx.x, lane = tid & 63, wv = tid >> 6;
    int fr = lane & 15, fq = lane >> 4;
    int wm = wv >> 1, wn = wv & 1;

    int fid = blockIdx.x;
    int xcd = fid & 7, w = fid >> 3;
    int slab = w / nb, n = w - slab * nb;    // n-inner within each XCD slab
    int mtile = slab * 8 + xcd;
    if (mtile >= mtiles) return;
    int m0 = mtile * (MBL * 16), n0 = n * (NBL * 16);

    int Kf = K >> 5;
    size_t tstr = (size_t)Kf * 512;

    // staging pointers: blob bi = wv + i*4; [0,MBL)=A-blobs, rest B-blobs
    const u16* gp[NST];
    u16* ldst[NST];
    #pragma unroll
    for (int i = 0; i < NST; ++i) {
        int bi = wv + i * 4;
        gp[i] = (bi < MBL)
            ? Ab + ((size_t)(m0 >> 4) + bi) * tstr + lane * 8
            : Bb + ((size_t)(n0 >> 4) + (bi - MBL)) * tstr + lane * 8;
        ldst[i] = smem + bi * 512;
    }

    f32x4 acc[MH2][NW2];
    #pragma unroll
    for (int mi = 0; mi < MH2; ++mi)
        #pragma unroll
        for (int ni = 0; ni < NW2; ++ni) acc[mi][ni] = (f32x4){0.f, 0.f, 0.f, 0.f};

    #pragma unroll
    for (int i = 0; i < NST; ++i) load_lds16(gp[i], ldst[i]);
    __syncthreads();

    for (int t = 0; t < Kf; ++t) {
        int cur = (t & 1) * BUFU, nxt = ((t + 1) & 1) * BUFU;
        if (t + 1 < Kf) {
            #pragma unroll
            for (int i = 0; i < NST; ++i)
                load_lds16(gp[i] + (size_t)(t + 1) * 512, ldst[i] + nxt);
        }
        bf16x8 a[MH2], bfr[NW2];
        #pragma unroll
        for (int mi = 0; mi < MH2; ++mi)
            a[mi] = *(const bf16x8*)(smem + cur + (wm * MH2 + mi) * 512 + lane * 8);
        #pragma unroll
        for (int ni = 0; ni < NW2; ++ni)
            bfr[ni] = *(const bf16x8*)(smem + cur + (MBL + wn * NW2 + ni) * 512 + lane * 8);
        #pragma unroll
        for (int mi = 0; mi < MH2; ++mi)
            #pragma unroll
            for (int ni = 0; ni < NW2; ++ni)
                acc[mi][ni] = __builtin_amdgcn_mfma_f32_16x16x32_bf16(
                    a[mi], bfr[ni], acc[mi][ni], 0, 0, 0);
        __syncthreads();
    }

    int m0w = m0 + wm * (MH2 * 16);
    int n0w = n0 + wn * (NW2 * 16);
    float* outf = (float*)outv;
    u16* outblob = (u16*)outv;

    if constexpr ((FLAGS & 8) != 0) {
        // qkv scatter: wave's 64-col span is one (sec, head), uniform per wave
        int sec = n0w / CDIM;
        int h   = (n0w % CDIM) / 64;
        #pragma unroll
        for (int mi = 0; mi < MH2; ++mi) {
            #pragma unroll
            for (int rg = 0; rg < 4; ++rg) {
                int gm = m0w + mi * 16 + fq * 4 + rg;
                if (gm >= M) continue;
                int b   = gm / NTOK;
                int row = gm - b * NTOK;
                int bh  = b * NH + h;
                #pragma unroll
                for (int ni = 0; ni < NW2; ++ni) {
                    int d = ni * 16 + fr;
                    float v = acc[mi][ni][rg] + bias[n0w + d];
                    __hip_bfloat16 hb = __float2bfloat16(v);
                    if (sec == 0) {
                        Qp[(size_t)(bh * QT + (row >> 4)) * 1024 + (d >> 5) * 512 +
                           (((d >> 3) & 3) * 16 + (row & 15)) * 8 + (d & 7)] = *(u16*)&hb;
                    } else if (sec == 1) {
                        Kp[(size_t)(bh * QT + (row >> 4)) * 1024 + (d >> 5) * 512 +
                           (((d >> 3) & 3) * 16 + (row & 15)) * 8 + (d & 7)] = *(u16*)&hb;
                    } else {
                        Vp[((size_t)(bh * 4 + (d >> 4)) * 20 + (row >> 5)) * 512 +
                           (((row >> 3) & 3) * 16 + (d & 15)) * 8 + (row & 7)] = *(u16*)&hb;
                    }
                }
            }
        }
        return;
    }

    if constexpr ((FLAGS & 4) != 0) {
        // blob out: per-wave private 2KB LDS staging per m-blob (wave-sync:
        // same wave writes then reads, program order), then linear 16B stores.
        u16* sb = smem + wv * 1024;
        int KfO = Nc >> 5;
        #pragma unroll
        for (int mi = 0; mi < MH2; ++mi) {
            #pragma unroll
            for (int ni = 0; ni < NW2; ++ni)
                #pragma unroll
                for (int rg = 0; rg < 4; ++rg) {
                    int cl = ni * 16 + fr;
                    float v = acc[mi][ni][rg] + bias[n0w + cl];
                    if (FLAGS & 1) v = fast_gelu(v);
                    __hip_bfloat16 hb = __float2bfloat16(v);
                    sb[(cl >> 5) * 512 +
                       (((cl >> 3) & 3) * 16 + fq * 4 + rg) * 8 + (cl & 7)] = *(u16*)&hb;
                }
            u16* dst = outblob + ((size_t)((m0w >> 4) + mi) * KfO + (n0w >> 5)) * 512;
            *(bf16x8*)(dst + lane * 16)     = *(const bf16x8*)(sb + lane * 16);
            *(bf16x8*)(dst + lane * 16 + 8) = *(const bf16x8*)(sb + lane * 16 + 8);
        }
        return;
    }

    #pragma unroll
    for (int mi = 0; mi < MH2; ++mi) {
        #pragma unroll
        for (int rg = 0; rg < 4; ++rg) {
            int gm = m0w + mi * 16 + fq * 4 + rg;
            if (gm >= M) continue;
            #pragma unroll
            for (int ni = 0; ni < NW2; ++ni) {
                int gn = n0w + ni * 16 + fr;
                float v = acc[mi][ni][rg] + bias[gn];
                if (res) v += res[(size_t)gm * Nc + gn];
                outf[(size_t)gm * Nc + gn] = v;
            }
        }
    }
}

// ---------------------------------------------------------------------------
// MFMA flash attention; output written in fragment-blob order (proj's A).
// 1-D grid, XCD-swizzled: xcd = fid&7 owns heads [xcd*24, xcd*24+24);
// qc is the INNER index so one head's 160KB K/V stream stays hot in that
// XCD's L2 across its 10 q-chunks (cuts ~4x K/V over-fetch).
// ---------------------------------------------------------------------------
__global__ __launch_bounds__(256) void attn_mfma(
    const u16* __restrict__ Qp, const u16* __restrict__ Kp,
    const u16* __restrict__ Vp, u16* __restrict__ outp)
{
    __shared__ __align__(16) u16 Ks[4096];
    __shared__ __align__(16) u16 Vs[4096];
    __shared__ __align__(16) u16 Ps[4 * 16 * 72];

    int fid = blockIdx.x;
    int xcd = fid & 7, w = fid >> 3;       // w in [0, 240)
    int bhl = w / 10, qc = w - bhl * 10;   // qc-inner
    int bh = xcd * 24 + bhl;
    int b = bh / NH, h = bh % NH;
    int t = threadIdx.x, lane = t & 63, wv = t >> 6;
    int fr = lane & 15, fq = lane >> 4;

    int mt = qc * 4 + wv;
    const u16* qbase = Qp + (size_t)(bh * QT + mt) * 1024 + lane * 8;
    bf16x8 qf0 = *(const bf16x8*)(qbase);
    bf16x8 qf1 = *(const bf16x8*)(qbase + 512);

    const u16* kg = Kp + (size_t)bh * (QT * 1024) + wv * 1024 + lane * 8;
    const u16* vg = Vp + ((size_t)(bh * 4 + wv) * 20) * 512 + lane * 8;
    u16* lK  = Ks + wv * 1024;
    u16* lV  = Vs + wv * 1024;
    u16* psw = Ps + wv * (16 * 72);

    f32x4 o[4];
    float m_r[4], l_r[4];
    #pragma unroll
    for (int i = 0; i < 4; ++i) {
        o[i] = (f32x4){0.f, 0.f, 0.f, 0.f};
        m_r[i] = -1e30f; l_r[i] = 0.f;
    }

    for (int kt = 0; kt < 10; ++kt) {
        load_lds16(kg + kt * 4096,       lK);
        load_lds16(kg + kt * 4096 + 512, lK + 512);
        load_lds16(vg + kt * 1024,       lV);
        load_lds16(vg + kt * 1024 + 512, lV + 512);
        __syncthreads();

        f32x4 sc[4];
        #pragma unroll
        for (int nt = 0; nt < 4; ++nt) {
            sc[nt] = (f32x4){0.f, 0.f, 0.f, 0.f};
            bf16x8 kf0 = *(const bf16x8*)(Ks + (nt * 2 + 0) * 512 + lane * 8);
            bf16x8 kf1 = *(const bf16x8*)(Ks + (nt * 2 + 1) * 512 + lane * 8);
            sc[nt] = __builtin_amdgcn_mfma_f32_16x16x32_bf16(qf0, kf0, sc[nt], 0, 0, 0);
            sc[nt] = __builtin_amdgcn_mfma_f32_16x16x32_bf16(qf1, kf1, sc[nt], 0, 0, 0);
        }

        int j0 = kt * 64;
        float p[4][4], rm[4];
        #pragma unroll
        for (int rg = 0; rg < 4; ++rg) rm[rg] = -1e30f;
        #pragma unroll
        for (int nt = 0; nt < 4; ++nt) {
            bool valid = (j0 + nt * 16 + fr) < NTOK;
            #pragma unroll
            for (int rg = 0; rg < 4; ++rg) {
                float sv = valid ? sc[nt][rg] * 0.125f : -1e30f;
                p[nt][rg] = sv;
                rm[rg] = fmaxf(rm[rg], sv);
            }
        }
        #pragma unroll
        for (int rg = 0; rg < 4; ++rg) {
            #pragma unroll
            for (int off = 1; off < 16; off <<= 1)
                rm[rg] = fmaxf(rm[rg], __shfl_xor(rm[rg], off));
        }
        float alpha[4], rs[4];
        #pragma unroll
        for (int rg = 0; rg < 4; ++rg) {
            float mn = fmaxf(m_r[rg], rm[rg]);
            alpha[rg] = __expf(m_r[rg] - mn);
            m_r[rg] = mn;
            rs[rg] = 0.f;
        }
        #pragma unroll
        for (int nt = 0; nt < 4; ++nt)
            #pragma unroll
            for (int rg = 0; rg < 4; ++rg) {
                float pv = __expf(p[nt][rg] - m_r[rg]);
                p[nt][rg] = pv;
                rs[rg] += pv;
            }
        #pragma unroll
        for (int rg = 0; rg < 4; ++rg) {
            #pragma unroll
            for (int off = 1; off < 16; off <<= 1)
                rs[rg] += __shfl_xor(rs[rg], off);
            l_r[rg] = l_r[rg] * alpha[rg] + rs[rg];
        }

        #pragma unroll
        for (int nt = 0; nt < 4; ++nt)
            #pragma unroll
            for (int rg = 0; rg < 4; ++rg) {
                __hip_bfloat16 hb = __float2bfloat16(p[nt][rg]);
                psw[(fq * 4 + rg) * 72 + nt * 16 + fr] = *(u16*)&hb;
            }
        #pragma unroll
        for (int dt = 0; dt < 4; ++dt)
            #pragma unroll
            for (int rg = 0; rg < 4; ++rg)
                o[dt][rg] *= alpha[rg];

        bf16x8 pf0 = *(const bf16x8*)(psw + fr * 72 + fq * 8);
        bf16x8 pf1 = *(const bf16x8*)(psw + fr * 72 + 32 + fq * 8);
        #pragma unroll
        for (int dt = 0; dt < 4; ++dt) {
            bf16x8 bv0 = *(const bf16x8*)(Vs + (dt * 2 + 0) * 512 + lane * 8);
            bf16x8 bv1 = *(const bf16x8*)(Vs + (dt * 2 + 1) * 512 + lane * 8);
            o[dt] = __builtin_amdgcn_mfma_f32_16x16x32_bf16(pf0, bv0, o[dt], 0, 0, 0);
            o[dt] = __builtin_amdgcn_mfma_f32_16x16x32_bf16(pf1, bv1, o[dt], 0, 0, 0);
        }
        __syncthreads();
    }

    #pragma unroll
    for (int rg = 0; rg < 4; ++rg) {
        int row = qc * 64 + wv * 16 + fq * 4 + rg;
        if (row < NTOK) {
            float rl = 1.0f / l_r[rg];
            int grow = b * NTOK + row;
            #pragma unroll
            for (int dt = 0; dt < 4; ++dt) {
                __hip_bfloat16 hb = __float2bfloat16(o[dt][rg] * rl);
                outp[blobA(grow, h * 64 + dt * 16 + fr, KF_C)] = *(u16*)&hb;
            }
        }
    }
}

// ---------------------------------------------------------------------------
static inline int tg_grid(int nb, int mt) { return 8 * nb * ((mt + 7) / 8); }

extern "C" void kernel_launch(void* const* d_in, const int* in_sizes, int n_in,
                              void* d_out, int out_size, void* d_ws, size_t ws_size,
                              hipStream_t stream)
{
    const float* x      = (const float*)d_in[0];
    const float* ln1_g  = (const float*)d_in[1];
    const float* ln1_b  = (const float*)d_in[2];
    const float* w_qkv  = (const float*)d_in[3];
    const float* b_qkv  = (const float*)d_in[4];
    const float* w_proj = (const float*)d_in[5];
    const float* b_proj = (const float*)d_in[6];
    const float* ln2_g  = (const float*)d_in[7];
    const float* ln2_b  = (const float*)d_in[8];
    const float* w_fc1  = (const float*)d_in[9];
    const float* b_fc1  = (const float*)d_in[10];
    const float* w_fc2  = (const float*)d_in[11];
    const float* b_fc2  = (const float*)d_in[12];
    float* out = (float*)d_out;

    char* w = (char*)d_ws;
    u16* Bqkv = (u16*)w; w += (size_t)3*CDIM*CDIM*2;
    u16* Bproj= (u16*)w; w += (size_t)CDIM*CDIM*2;
    u16* Bfc1 = (u16*)w; w += (size_t)HID*CDIM*2;
    u16* Bfc2 = (u16*)w; w += (size_t)CDIM*HID*2;
    u16* hA   = (u16*)w; w += (size_t)RPAD*CDIM*2;   // blob activations (768)
    u16* h3A  = (u16*)w; w += (size_t)RPAD*HID*2;    // blob activations (3072)
    u16* Qp   = (u16*)w; w += (size_t)BH*QT*1024*2;
    u16* Kp   = (u16*)w; w += (size_t)BH*QT*1024*2;
    u16* Vp   = (u16*)w; w += (size_t)BH*4*20*512*2;

    int mt128 = (RTOT + 127) / 128;   // 73  (73*128 = 9344 = RPAD: reads in-bounds)
    int mt64  = (RTOT + 63) / 64;     // 145

    // 0. weights -> fragment blobs
    wconvert_blob<<<dim3(3*CDIM/256, CDIM/8), 256, 0, stream>>>(w_qkv,  Bqkv, CDIM, 3*CDIM);
    wconvert_blob<<<dim3(CDIM/256,   CDIM/8), 256, 0, stream>>>(w_proj, Bproj, CDIM, CDIM);
    wconvert_blob<<<dim3(HID/256,    CDIM/8), 256, 0, stream>>>(w_fc1,  Bfc1, CDIM, HID);
    wconvert_blob<<<dim3(CDIM/256,   HID/8),  256, 0, stream>>>(w_fc2,  Bfc2, HID, CDIM);

    // 1. hA = LN1(x)  (blob)
    ln_kernel<<<RTOT, 256, 0, stream>>>(x, ln1_g, ln1_b, hA);
    // 2. qkv GEMM -> Q/K/V blobs  (128x128 tiles, swizzled 18x73)
    tile_gemm<8, 8, 8><<<tg_grid(3*CDIM/128, mt128), 256, 0, stream>>>(
        hA, Bqkv, b_qkv, nullptr, nullptr, Qp, Kp, Vp,
        RTOT, 3*CDIM, CDIM, 3*CDIM/128, mt128);
    // 3. attention -> hA (blob)
    attn_mfma<<<8 * 24 * 10, 256, 0, stream>>>(Qp, Kp, Vp, hA);
    // 4. x1 = x + hA @ Bproj^T + b_proj -> d_out (fp32; 64x128, swizzled 6x145)
    tile_gemm<4, 8, 0><<<tg_grid(CDIM/128, mt64), 256, 0, stream>>>(
        hA, Bproj, b_proj, x, out, nullptr, nullptr, nullptr,
        RTOT, CDIM, CDIM, CDIM/128, mt64);
    // 5. hA = LN2(x1)  (blob)
    ln_kernel<<<RTOT, 256, 0, stream>>>(out, ln2_g, ln2_b, hA);
    // 6. h3A = gelu(hA @ Bfc1^T + b_fc1)  (blob out; 128x128, swizzled 24x73)
    tile_gemm<8, 8, 5><<<tg_grid(HID/128, mt128), 256, 0, stream>>>(
        hA, Bfc1, b_fc1, nullptr, h3A, nullptr, nullptr, nullptr,
        RTOT, HID, CDIM, HID/128, mt128);
    // 7. out = x1 + h3A @ Bfc2^T + b_fc2  (fp32; 64x128, swizzled 6x145)
    tile_gemm<4, 8, 0><<<tg_grid(CDIM/128, mt64), 256, 0, stream>>>(
        h3A, Bfc2, b_fc2, out, out, nullptr, nullptr, nullptr,
        RTOT, CDIM, HID, CDIM/128, mt64);
}

// Round 8
// 451.205 us; speedup vs baseline: 1.2288x; 1.0315x over previous
//
#include <hip/hip_runtime.h>
#include <hip/hip_bf16.h>
#include <math.h>

#define NB   16
#define NTOK 577
#define CDIM 768
#define NH   12
#define HID  3072
#define RTOT (NB*NTOK)        // 9232
#define RPAD (((RTOT+127)/128)*128) // 9344
#define BH   (NB*NH)          // 192
#define QT   40               // 640/16 fragment-tiles per (b,h)
#define KF_C (CDIM/32)        // 24

typedef __attribute__((ext_vector_type(8))) short bf16x8;
typedef __attribute__((ext_vector_type(4))) float f32x4;
typedef unsigned short u16;

__device__ inline void load_lds16(const void* g, void* l) {
    __builtin_amdgcn_global_load_lds(
        (const __attribute__((address_space(1))) unsigned*)g,
        (__attribute__((address_space(3))) unsigned*)l, 16, 0, 0);
}

// fragment-blob address for element (m, c) of an [M][C] bf16 matrix packed in
// MFMA A-operand order: blob(mt, kf) is 512 u16, lane(fq*16+fr) holds 8 elems.
__device__ inline size_t blobA(int m, int c, int Kf) {
    return ((size_t)(m >> 4) * Kf + (c >> 5)) * 512 +
           (((c >> 3) & 3) * 16 + (m & 15)) * 8 + (c & 7);
}

// exp-based tanh gelu
__device__ inline float fast_gelu(float x) {
    float y = 0.7978845608f * (x + 0.044715f * x * x * x);
    float e = __expf(2.0f * y);
    float th = 1.0f - 2.0f / (e + 1.0f);
    return 0.5f * x * (1.0f + th);
}

// ---------------------------------------------------------------------------
// Weight fp32 [K][N] -> bf16 fragment blobs (B-operand: roles m->n, c->k).
// ---------------------------------------------------------------------------
__global__ __launch_bounds__(256) void wconvert_blob(
    const float* __restrict__ src, u16* __restrict__ dst, int K, int N)
{
    int n  = blockIdx.x * 256 + threadIdx.x;
    int kp = blockIdx.y;                     // k-chunk of 8
    const float* s = src + (size_t)(kp * 8) * N + n;
    __hip_bfloat16 h0 = __float2bfloat16(s[0 * N]);
    __hip_bfloat16 h1 = __float2bfloat16(s[1 * N]);
    __hip_bfloat16 h2 = __float2bfloat16(s[2 * N]);
    __hip_bfloat16 h3 = __float2bfloat16(s[3 * N]);
    __hip_bfloat16 h4 = __float2bfloat16(s[4 * N]);
    __hip_bfloat16 h5 = __float2bfloat16(s[5 * N]);
    __hip_bfloat16 h6 = __float2bfloat16(s[6 * N]);
    __hip_bfloat16 h7 = __float2bfloat16(s[7 * N]);
    ushort4 a = make_ushort4(*(u16*)&h0, *(u16*)&h1, *(u16*)&h2, *(u16*)&h3);
    ushort4 b = make_ushort4(*(u16*)&h4, *(u16*)&h5, *(u16*)&h6, *(u16*)&h7);
    u16* d = dst + ((size_t)(n >> 4) * (K >> 5) + (kp >> 2)) * 512 +
             ((kp & 3) * 16 + (n & 15)) * 8;
    *(ushort4*)(d)     = a;
    *(ushort4*)(d + 4) = b;
}

// ---------------------------------------------------------------------------
// LayerNorm -> bf16 fragment blob (Kf = 24). Values staged in an LDS row
// buffer, then written as blob-contiguous 16B stores (chunk of 8 c's is one
// bf16x8 in blob space) — replaces 3 scattered scalar u16 stores/thread.
// ---------------------------------------------------------------------------
__global__ __launch_bounds__(256) void ln_kernel(
    const float* __restrict__ x, const float* __restrict__ g,
    const float* __restrict__ b, u16* __restrict__ out)
{
    int row = blockIdx.x;
    const float* xr = x + (size_t)row * CDIM;
    int t = threadIdx.x;
    float v0 = xr[t], v1 = xr[t + 256], v2 = xr[t + 512];
    float s  = v0 + v1 + v2;
    float s2 = v0*v0 + v1*v1 + v2*v2;
    #pragma unroll
    for (int off = 32; off; off >>= 1) {
        s  += __shfl_xor(s, off);
        s2 += __shfl_xor(s2, off);
    }
    __shared__ float red[10];
    __shared__ __align__(16) u16 rowbuf[CDIM];
    int wave = t >> 6, lane = t & 63;
    if (lane == 0) { red[wave] = s; red[wave + 4] = s2; }
    __syncthreads();
    if (t == 0) {
        float ts  = red[0] + red[1] + red[2] + red[3];
        float ts2 = red[4] + red[5] + red[6] + red[7];
        float mu  = ts * (1.0f / CDIM);
        float var = ts2 * (1.0f / CDIM) - mu * mu;
        red[8] = mu;
        red[9] = rsqrtf(var + 1e-5f);
    }
    __syncthreads();
    float mu = red[8], rs = red[9];
    #pragma unroll
    for (int i = 0; i < 3; ++i) {
        int c = t + i * 256;
        float v = (i == 0 ? v0 : (i == 1 ? v1 : v2));
        __hip_bfloat16 hb = __float2bfloat16((v - mu) * rs * g[c] + b[c]);
        rowbuf[c] = *(u16*)&hb;
    }
    __syncthreads();
    if (t < CDIM / 8) {
        int c0 = t * 8;
        *(bf16x8*)(out + blobA(row, c0, KF_C)) = *(const bf16x8*)(rowbuf + c0);
    }
}

// ---------------------------------------------------------------------------
// LDS-staged 4-wave GEMM (m97 structure) with XCD-slab swizzle.
// Block tile = (MBL*16) x (NBL*16), BK = 32 (one blob column per step).
// 1-D grid: xcd = fid&7 picks the m-slab residue; within an XCD the n-index
// is the INNER loop so one A-panel stays hot in that XCD's L2 while the
// B-strips sweep (R2-proven: brings FETCH to ~compulsory).
// 2x2 wave grid: wave (wm, wn) owns MBL/2 x NBL/2 blobs. Per K-step: each
// wave DMAs (MBL+NBL)/4 next-step blobs via global_load_lds (wave-uniform
// dest + lane*16B: blob format IS the linear order), ds_read_b128 current
// fragments, MFMAs, one __syncthreads.
// FLAGS: 1=gelu, 4=blob out, 8=qkv scatter, else fp32 out (+res).
// ---------------------------------------------------------------------------
template<int MBL, int NBL, int FLAGS>
__global__ __launch_bounds__(256) void tile_gemm(
    const u16* __restrict__ Ab, const u16* __restrict__ Bb,
    const float* __restrict__ bias, const float* __restrict__ res,
    void* __restrict__ outv,
    u16* __restrict__ Qp, u16* __restrict__ Kp, u16* __restrict__ Vp,
    int M, int Nc, int K, int nb, int mtiles)
{
    constexpr int NST  = (MBL + NBL) / 4;   // DMA blobs per wave per step
    constexpr int BUFU = (MBL + NBL) * 512; // u16 per buffer
    constexpr int MH2  = MBL / 2, NW2 = NBL / 2;
    __shared__ __align__(16) u16 smem[2 * BUFU];

    int tid = threadIdx.x, lane = tid & 63, wv = tid >> 6;
    int fr = lane & 15, fq = lane >> 4;
    int wm = wv >> 1, wn = wv & 1;

    int fid = blockIdx.x;
    int xcd = fid & 7, w = fid >> 3;
    int slab = w / nb, n = w - slab * nb;    // n-inner within each XCD slab
    int mtile = slab * 8 + xcd;
    if (mtile >= mtiles) return;
    int m0 = mtile * (MBL * 16), n0 = n * (NBL * 16);

    int Kf = K >> 5;
    size_t tstr = (size_t)Kf * 512;

    // staging pointers: blob bi = wv + i*4; [0,MBL)=A-blobs, rest B-blobs
    const u16* gp[NST];
    u16* ldst[NST];
    #pragma unroll
    for (int i = 0; i < NST; ++i) {
        int bi = wv + i * 4;
        gp[i] = (bi < MBL)
            ? Ab + ((size_t)(m0 >> 4) + bi) * tstr + lane * 8
            : Bb + ((size_t)(n0 >> 4) + (bi - MBL)) * tstr + lane * 8;
        ldst[i] = smem + bi * 512;
    }

    f32x4 acc[MH2][NW2];
    #pragma unroll
    for (int mi = 0; mi < MH2; ++mi)
        #pragma unroll
        for (int ni = 0; ni < NW2; ++ni) acc[mi][ni] = (f32x4){0.f, 0.f, 0.f, 0.f};

    #pragma unroll
    for (int i = 0; i < NST; ++i) load_lds16(gp[i], ldst[i]);
    __syncthreads();

    for (int t = 0; t < Kf; ++t) {
        int cur = (t & 1) * BUFU, nxt = ((t + 1) & 1) * BUFU;
        if (t + 1 < Kf) {
            #pragma unroll
            for (int i = 0; i < NST; ++i)
                load_lds16(gp[i] + (size_t)(t + 1) * 512, ldst[i] + nxt);
        }
        bf16x8 a[MH2], bfr[NW2];
        #pragma unroll
        for (int mi = 0; mi < MH2; ++mi)
            a[mi] = *(const bf16x8*)(smem + cur + (wm * MH2 + mi) * 512 + lane * 8);
        #pragma unroll
        for (int ni = 0; ni < NW2; ++ni)
            bfr[ni] = *(const bf16x8*)(smem + cur + (MBL + wn * NW2 + ni) * 512 + lane * 8);
        #pragma unroll
        for (int mi = 0; mi < MH2; ++mi)
            #pragma unroll
            for (int ni = 0; ni < NW2; ++ni)
                acc[mi][ni] = __builtin_amdgcn_mfma_f32_16x16x32_bf16(
                    a[mi], bfr[ni], acc[mi][ni], 0, 0, 0);
        __syncthreads();
    }

    int m0w = m0 + wm * (MH2 * 16);
    int n0w = n0 + wn * (NW2 * 16);
    float* outf = (float*)outv;
    u16* outblob = (u16*)outv;

    if constexpr ((FLAGS & 8) != 0) {
        // qkv scatter: wave's 64-col span is one (sec, head), uniform per wave
        int sec = n0w / CDIM;
        int h   = (n0w % CDIM) / 64;
        #pragma unroll
        for (int mi = 0; mi < MH2; ++mi) {
            #pragma unroll
            for (int rg = 0; rg < 4; ++rg) {
                int gm = m0w + mi * 16 + fq * 4 + rg;
                if (gm >= M) continue;
                int b   = gm / NTOK;
                int row = gm - b * NTOK;
                int bh  = b * NH + h;
                #pragma unroll
                for (int ni = 0; ni < NW2; ++ni) {
                    int d = ni * 16 + fr;
                    float v = acc[mi][ni][rg] + bias[n0w + d];
                    __hip_bfloat16 hb = __float2bfloat16(v);
                    if (sec == 0) {
                        Qp[(size_t)(bh * QT + (row >> 4)) * 1024 + (d >> 5) * 512 +
                           (((d >> 3) & 3) * 16 + (row & 15)) * 8 + (d & 7)] = *(u16*)&hb;
                    } else if (sec == 1) {
                        Kp[(size_t)(bh * QT + (row >> 4)) * 1024 + (d >> 5) * 512 +
                           (((d >> 3) & 3) * 16 + (row & 15)) * 8 + (d & 7)] = *(u16*)&hb;
                    } else {
                        Vp[((size_t)(bh * 4 + (d >> 4)) * 20 + (row >> 5)) * 512 +
                           (((row >> 3) & 3) * 16 + (d & 15)) * 8 + (row & 7)] = *(u16*)&hb;
                    }
                }
            }
        }
        return;
    }

    if constexpr ((FLAGS & 4) != 0) {
        // blob out: per-wave private 2KB LDS staging per m-blob (wave-sync:
        // same wave writes then reads, program order), then linear 16B stores.
        u16* sb = smem + wv * 1024;
        int KfO = Nc >> 5;
        #pragma unroll
        for (int mi = 0; mi < MH2; ++mi) {
            #pragma unroll
            for (int ni = 0; ni < NW2; ++ni)
                #pragma unroll
                for (int rg = 0; rg < 4; ++rg) {
                    int cl = ni * 16 + fr;
                    float v = acc[mi][ni][rg] + bias[n0w + cl];
                    if (FLAGS & 1) v = fast_gelu(v);
                    __hip_bfloat16 hb = __float2bfloat16(v);
                    sb[(cl >> 5) * 512 +
                       (((cl >> 3) & 3) * 16 + fq * 4 + rg) * 8 + (cl & 7)] = *(u16*)&hb;
                }
            u16* dst = outblob + ((size_t)((m0w >> 4) + mi) * KfO + (n0w >> 5)) * 512;
            *(bf16x8*)(dst + lane * 16)     = *(const bf16x8*)(sb + lane * 16);
            *(bf16x8*)(dst + lane * 16 + 8) = *(const bf16x8*)(sb + lane * 16 + 8);
        }
        return;
    }

    #pragma unroll
    for (int mi = 0; mi < MH2; ++mi) {
        #pragma unroll
        for (int rg = 0; rg < 4; ++rg) {
            int gm = m0w + mi * 16 + fq * 4 + rg;
            if (gm >= M) continue;
            #pragma unroll
            for (int ni = 0; ni < NW2; ++ni) {
                int gn = n0w + ni * 16 + fr;
                float v = acc[mi][ni][rg] + bias[gn];
                if (res) v += res[(size_t)gm * Nc + gn];
                outf[(size_t)gm * Nc + gn] = v;
            }
        }
    }
}

// ---------------------------------------------------------------------------
// MFMA flash attention; output written in fragment-blob order (proj's A).
// XCD-swizzled 1-D grid (xcd owns 24 heads, qc-inner: K/V L2-hot — R5-proven,
// FETCH at compulsory). Double-buffered K/V staging — prefetch kt+1
// before computing kt so the L2 round-trip overlaps the softmax/MFMA chain
// (the end-of-step barrier drains the prefetch, tile_gemm pattern).
// s_setprio(1) around MFMA clusters (T5: independent blocks per CU).
// ---------------------------------------------------------------------------
__global__ __launch_bounds__(256) void attn_mfma(
    const u16* __restrict__ Qp, const u16* __restrict__ Kp,
    const u16* __restrict__ Vp, u16* __restrict__ outp)
{
    __shared__ __align__(16) u16 Ks[2][4096];
    __shared__ __align__(16) u16 Vs[2][4096];
    __shared__ __align__(16) u16 Ps[4 * 16 * 72];

    int fid = blockIdx.x;
    int xcd = fid & 7, w = fid >> 3;       // w in [0, 240)
    int bhl = w / 10, qc = w - bhl * 10;   // qc-inner
    int bh = xcd * 24 + bhl;
    int b = bh / NH, h = bh % NH;
    int t = threadIdx.x, lane = t & 63, wv = t >> 6;
    int fr = lane & 15, fq = lane >> 4;

    int mt = qc * 4 + wv;
    const u16* qbase = Qp + (size_t)(bh * QT + mt) * 1024 + lane * 8;
    bf16x8 qf0 = *(const bf16x8*)(qbase);
    bf16x8 qf1 = *(const bf16x8*)(qbase + 512);

    const u16* kg = Kp + (size_t)bh * (QT * 1024) + wv * 1024 + lane * 8;
    const u16* vg = Vp + ((size_t)(bh * 4 + wv) * 20) * 512 + lane * 8;
    u16* psw = Ps + wv * (16 * 72);

#define STAGE(buf, kt) do {                                        \
    load_lds16(kg + (kt) * 4096,       &Ks[buf][wv * 1024]);       \
    load_lds16(kg + (kt) * 4096 + 512, &Ks[buf][wv * 1024 + 512]); \
    load_lds16(vg + (kt) * 1024,       &Vs[buf][wv * 1024]);       \
    load_lds16(vg + (kt) * 1024 + 512, &Vs[buf][wv * 1024 + 512]); \
} while (0)

    f32x4 o[4];
    float m_r[4], l_r[4];
    #pragma unroll
    for (int i = 0; i < 4; ++i) {
        o[i] = (f32x4){0.f, 0.f, 0.f, 0.f};
        m_r[i] = -1e30f; l_r[i] = 0.f;
    }

    STAGE(0, 0);
    __syncthreads();

    for (int kt = 0; kt < 10; ++kt) {
        int cur = kt & 1;
        if (kt + 1 < 10) STAGE(cur ^ 1, kt + 1);

        f32x4 sc[4];
        __builtin_amdgcn_s_setprio(1);
        #pragma unroll
        for (int nt = 0; nt < 4; ++nt) {
            sc[nt] = (f32x4){0.f, 0.f, 0.f, 0.f};
            bf16x8 kf0 = *(const bf16x8*)(&Ks[cur][(nt * 2 + 0) * 512] + lane * 8);
            bf16x8 kf1 = *(const bf16x8*)(&Ks[cur][(nt * 2 + 1) * 512] + lane * 8);
            sc[nt] = __builtin_amdgcn_mfma_f32_16x16x32_bf16(qf0, kf0, sc[nt], 0, 0, 0);
            sc[nt] = __builtin_amdgcn_mfma_f32_16x16x32_bf16(qf1, kf1, sc[nt], 0, 0, 0);
        }
        __builtin_amdgcn_s_setprio(0);

        int j0 = kt * 64;
        float p[4][4], rm[4];
        #pragma unroll
        for (int rg = 0; rg < 4; ++rg) rm[rg] = -1e30f;
        #pragma unroll
        for (int nt = 0; nt < 4; ++nt) {
            bool valid = (j0 + nt * 16 + fr) < NTOK;
            #pragma unroll
            for (int rg = 0; rg < 4; ++rg) {
                float sv = valid ? sc[nt][rg] * 0.125f : -1e30f;
                p[nt][rg] = sv;
                rm[rg] = fmaxf(rm[rg], sv);
            }
        }
        #pragma unroll
        for (int rg = 0; rg < 4; ++rg) {
            #pragma unroll
            for (int off = 1; off < 16; off <<= 1)
                rm[rg] = fmaxf(rm[rg], __shfl_xor(rm[rg], off));
        }
        float alpha[4], rs[4];
        #pragma unroll
        for (int rg = 0; rg < 4; ++rg) {
            float mn = fmaxf(m_r[rg], rm[rg]);
            alpha[rg] = __expf(m_r[rg] - mn);
            m_r[rg] = mn;
            rs[rg] = 0.f;
        }
        #pragma unroll
        for (int nt = 0; nt < 4; ++nt)
            #pragma unroll
            for (int rg = 0; rg < 4; ++rg) {
                float pv = __expf(p[nt][rg] - m_r[rg]);
                p[nt][rg] = pv;
                rs[rg] += pv;
            }
        #pragma unroll
        for (int rg = 0; rg < 4; ++rg) {
            #pragma unroll
            for (int off = 1; off < 16; off <<= 1)
                rs[rg] += __shfl_xor(rs[rg], off);
            l_r[rg] = l_r[rg] * alpha[rg] + rs[rg];
        }

        #pragma unroll
        for (int nt = 0; nt < 4; ++nt)
            #pragma unroll
            for (int rg = 0; rg < 4; ++rg) {
                __hip_bfloat16 hb = __float2bfloat16(p[nt][rg]);
                psw[(fq * 4 + rg) * 72 + nt * 16 + fr] = *(u16*)&hb;
            }
        #pragma unroll
        for (int dt = 0; dt < 4; ++dt)
            #pragma unroll
            for (int rg = 0; rg < 4; ++rg)
                o[dt][rg] *= alpha[rg];

        bf16x8 pf0 = *(const bf16x8*)(psw + fr * 72 + fq * 8);
        bf16x8 pf1 = *(const bf16x8*)(psw + fr * 72 + 32 + fq * 8);
        __builtin_amdgcn_s_setprio(1);
        #pragma unroll
        for (int dt = 0; dt < 4; ++dt) {
            bf16x8 bv0 = *(const bf16x8*)(&Vs[cur][(dt * 2 + 0) * 512] + lane * 8);
            bf16x8 bv1 = *(const bf16x8*)(&Vs[cur][(dt * 2 + 1) * 512] + lane * 8);
            o[dt] = __builtin_amdgcn_mfma_f32_16x16x32_bf16(pf0, bv0, o[dt], 0, 0, 0);
            o[dt] = __builtin_amdgcn_mfma_f32_16x16x32_bf16(pf1, bv1, o[dt], 0, 0, 0);
        }
        __builtin_amdgcn_s_setprio(0);
        __syncthreads();   // drains this step's prefetch + read-sync of cur
    }
#undef STAGE

    #pragma unroll
    for (int rg = 0; rg < 4; ++rg) {
        int row = qc * 64 + wv * 16 + fq * 4 + rg;
        if (row < NTOK) {
            float rl = 1.0f / l_r[rg];
            int grow = b * NTOK + row;
            #pragma unroll
            for (int dt = 0; dt < 4; ++dt) {
                __hip_bfloat16 hb = __float2bfloat16(o[dt][rg] * rl);
                outp[blobA(grow, h * 64 + dt * 16 + fr, KF_C)] = *(u16*)&hb;
            }
        }
    }
}

// ---------------------------------------------------------------------------
static inline int tg_grid(int nb, int mt) { return 8 * nb * ((mt + 7) / 8); }

extern "C" void kernel_launch(void* const* d_in, const int* in_sizes, int n_in,
                              void* d_out, int out_size, void* d_ws, size_t ws_size,
                              hipStream_t stream)
{
    const float* x      = (const float*)d_in[0];
    const float* ln1_g  = (const float*)d_in[1];
    const float* ln1_b  = (const float*)d_in[2];
    const float* w_qkv  = (const float*)d_in[3];
    const float* b_qkv  = (const float*)d_in[4];
    const float* w_proj = (const float*)d_in[5];
    const float* b_proj = (const float*)d_in[6];
    const float* ln2_g  = (const float*)d_in[7];
    const float* ln2_b  = (const float*)d_in[8];
    const float* w_fc1  = (const float*)d_in[9];
    const float* b_fc1  = (const float*)d_in[10];
    const float* w_fc2  = (const float*)d_in[11];
    const float* b_fc2  = (const float*)d_in[12];
    float* out = (float*)d_out;

    char* w = (char*)d_ws;
    u16* Bqkv = (u16*)w; w += (size_t)3*CDIM*CDIM*2;
    u16* Bproj= (u16*)w; w += (size_t)CDIM*CDIM*2;
    u16* Bfc1 = (u16*)w; w += (size_t)HID*CDIM*2;
    u16* Bfc2 = (u16*)w; w += (size_t)CDIM*HID*2;
    u16* hA   = (u16*)w; w += (size_t)RPAD*CDIM*2;   // blob activations (768)
    u16* h3A  = (u16*)w; w += (size_t)RPAD*HID*2;    // blob activations (3072)
    u16* Qp   = (u16*)w; w += (size_t)BH*QT*1024*2;
    u16* Kp   = (u16*)w; w += (size_t)BH*QT*1024*2;
    u16* Vp   = (u16*)w; w += (size_t)BH*4*20*512*2;

    int mt128 = (RTOT + 127) / 128;   // 73  (73*128 = 9344 = RPAD: reads in-bounds)
    int mt64  = (RTOT + 63) / 64;     // 145

    // 0. weights -> fragment blobs
    wconvert_blob<<<dim3(3*CDIM/256, CDIM/8), 256, 0, stream>>>(w_qkv,  Bqkv, CDIM, 3*CDIM);
    wconvert_blob<<<dim3(CDIM/256,   CDIM/8), 256, 0, stream>>>(w_proj, Bproj, CDIM, CDIM);
    wconvert_blob<<<dim3(HID/256,    CDIM/8), 256, 0, stream>>>(w_fc1,  Bfc1, CDIM, HID);
    wconvert_blob<<<dim3(CDIM/256,   HID/8),  256, 0, stream>>>(w_fc2,  Bfc2, HID, CDIM);

    // 1. hA = LN1(x)  (blob)
    ln_kernel<<<RTOT, 256, 0, stream>>>(x, ln1_g, ln1_b, hA);
    // 2. qkv GEMM -> Q/K/V blobs  (128x128 tiles, swizzled 18x73)
    tile_gemm<8, 8, 8><<<tg_grid(3*CDIM/128, mt128), 256, 0, stream>>>(
        hA, Bqkv, b_qkv, nullptr, nullptr, Qp, Kp, Vp,
        RTOT, 3*CDIM, CDIM, 3*CDIM/128, mt128);
    // 3. attention -> hA (blob)
    attn_mfma<<<8 * 24 * 10, 256, 0, stream>>>(Qp, Kp, Vp, hA);
    // 4. x1 = x + hA @ Bproj^T + b_proj -> d_out (fp32; 64x128, swizzled 6x145)
    tile_gemm<4, 8, 0><<<tg_grid(CDIM/128, mt64), 256, 0, stream>>>(
        hA, Bproj, b_proj, x, out, nullptr, nullptr, nullptr,
        RTOT, CDIM, CDIM, CDIM/128, mt64);
    // 5. hA = LN2(x1)  (blob)
    ln_kernel<<<RTOT, 256, 0, stream>>>(out, ln2_g, ln2_b, hA);
    // 6. h3A = gelu(hA @ Bfc1^T + b_fc1)  (blob out; 128x128, swizzled 24x73)
    tile_gemm<8, 8, 5><<<tg_grid(HID/128, mt128), 256, 0, stream>>>(
        hA, Bfc1, b_fc1, nullptr, h3A, nullptr, nullptr, nullptr,
        RTOT, HID, CDIM, HID/128, mt128);
    // 7. out = x1 + h3A @ Bfc2^T + b_fc2  (fp32; 64x128, swizzled 6x145)
    tile_gemm<4, 8, 0><<<tg_grid(CDIM/128, mt64), 256, 0, stream>>>(
        h3A, Bfc2, b_fc2, out, out, nullptr, nullptr, nullptr,
        RTOT, CDIM, HID, CDIM/128, mt64);
}

// Round 9
// 423.523 us; speedup vs baseline: 1.3091x; 1.0654x over previous
//
#include <hip/hip_runtime.h>
#include <hip/hip_bf16.h>
#include <math.h>

#define NB   16
#define NTOK 577
#define CDIM 768
#define NH   12
#define HID  3072
#define RTOT (NB*NTOK)        // 9232
#define RPAD (((RTOT+127)/128)*128) // 9344
#define BH   (NB*NH)          // 192
#define QT   40               // 640/16 fragment-tiles per (b,h)
#define KF_C (CDIM/32)        // 24

typedef __attribute__((ext_vector_type(8))) short bf16x8;
typedef __attribute__((ext_vector_type(4))) float f32x4;
typedef unsigned short u16;

__device__ inline void load_lds16(const void* g, void* l) {
    __builtin_amdgcn_global_load_lds(
        (const __attribute__((address_space(1))) unsigned*)g,
        (__attribute__((address_space(3))) unsigned*)l, 16, 0, 0);
}

// fragment-blob address for element (m, c) of an [M][C] bf16 matrix packed in
// MFMA A-operand order: blob(mt, kf) is 512 u16, lane(fq*16+fr) holds 8 elems.
__device__ inline size_t blobA(int m, int c, int Kf) {
    return ((size_t)(m >> 4) * Kf + (c >> 5)) * 512 +
           (((c >> 3) & 3) * 16 + (m & 15)) * 8 + (c & 7);
}

// exp-based tanh gelu
__device__ inline float fast_gelu(float x) {
    float y = 0.7978845608f * (x + 0.044715f * x * x * x);
    float e = __expf(2.0f * y);
    float th = 1.0f - 2.0f / (e + 1.0f);
    return 0.5f * x * (1.0f + th);
}

// ---------------------------------------------------------------------------
// Weight fp32 [K][N] -> bf16 fragment blobs (B-operand: roles m->n, c->k).
// ---------------------------------------------------------------------------
__global__ __launch_bounds__(256) void wconvert_blob(
    const float* __restrict__ src, u16* __restrict__ dst, int K, int N)
{
    int n  = blockIdx.x * 256 + threadIdx.x;
    int kp = blockIdx.y;                     // k-chunk of 8
    const float* s = src + (size_t)(kp * 8) * N + n;
    __hip_bfloat16 h0 = __float2bfloat16(s[0 * N]);
    __hip_bfloat16 h1 = __float2bfloat16(s[1 * N]);
    __hip_bfloat16 h2 = __float2bfloat16(s[2 * N]);
    __hip_bfloat16 h3 = __float2bfloat16(s[3 * N]);
    __hip_bfloat16 h4 = __float2bfloat16(s[4 * N]);
    __hip_bfloat16 h5 = __float2bfloat16(s[5 * N]);
    __hip_bfloat16 h6 = __float2bfloat16(s[6 * N]);
    __hip_bfloat16 h7 = __float2bfloat16(s[7 * N]);
    ushort4 a = make_ushort4(*(u16*)&h0, *(u16*)&h1, *(u16*)&h2, *(u16*)&h3);
    ushort4 b = make_ushort4(*(u16*)&h4, *(u16*)&h5, *(u16*)&h6, *(u16*)&h7);
    u16* d = dst + ((size_t)(n >> 4) * (K >> 5) + (kp >> 2)) * 512 +
             ((kp & 3) * 16 + (n & 15)) * 8;
    *(ushort4*)(d)     = a;
    *(ushort4*)(d + 4) = b;
}

// ---------------------------------------------------------------------------
// LayerNorm -> bf16 fragment blob (Kf = 24). Values staged in an LDS row
// buffer, then written as blob-contiguous 16B stores.
// ---------------------------------------------------------------------------
__global__ __launch_bounds__(256) void ln_kernel(
    const float* __restrict__ x, const float* __restrict__ g,
    const float* __restrict__ b, u16* __restrict__ out)
{
    int row = blockIdx.x;
    const float* xr = x + (size_t)row * CDIM;
    int t = threadIdx.x;
    float v0 = xr[t], v1 = xr[t + 256], v2 = xr[t + 512];
    float s  = v0 + v1 + v2;
    float s2 = v0*v0 + v1*v1 + v2*v2;
    #pragma unroll
    for (int off = 32; off; off >>= 1) {
        s  += __shfl_xor(s, off);
        s2 += __shfl_xor(s2, off);
    }
    __shared__ float red[10];
    __shared__ __align__(16) u16 rowbuf[CDIM];
    int wave = t >> 6, lane = t & 63;
    if (lane == 0) { red[wave] = s; red[wave + 4] = s2; }
    __syncthreads();
    if (t == 0) {
        float ts  = red[0] + red[1] + red[2] + red[3];
        float ts2 = red[4] + red[5] + red[6] + red[7];
        float mu  = ts * (1.0f / CDIM);
        float var = ts2 * (1.0f / CDIM) - mu * mu;
        red[8] = mu;
        red[9] = rsqrtf(var + 1e-5f);
    }
    __syncthreads();
    float mu = red[8], rs = red[9];
    #pragma unroll
    for (int i = 0; i < 3; ++i) {
        int c = t + i * 256;
        float v = (i == 0 ? v0 : (i == 1 ? v1 : v2));
        __hip_bfloat16 hb = __float2bfloat16((v - mu) * rs * g[c] + b[c]);
        rowbuf[c] = *(u16*)&hb;
    }
    __syncthreads();
    if (t < CDIM / 8) {
        int c0 = t * 8;
        *(bf16x8*)(out + blobA(row, c0, KF_C)) = *(const bf16x8*)(rowbuf + c0);
    }
}

// ---------------------------------------------------------------------------
// LDS-staged 4-wave GEMM (m97 structure) with XCD-slab swizzle.
// (unchanged from R5/R8 — see comments there)
// ---------------------------------------------------------------------------
template<int MBL, int NBL, int FLAGS>
__global__ __launch_bounds__(256) void tile_gemm(
    const u16* __restrict__ Ab, const u16* __restrict__ Bb,
    const float* __restrict__ bias, const float* __restrict__ res,
    void* __restrict__ outv,
    u16* __restrict__ Qp, u16* __restrict__ Kp, u16* __restrict__ Vp,
    int M, int Nc, int K, int nb, int mtiles)
{
    constexpr int NST  = (MBL + NBL) / 4;   // DMA blobs per wave per step
    constexpr int BUFU = (MBL + NBL) * 512; // u16 per buffer
    constexpr int MH2  = MBL / 2, NW2 = NBL / 2;
    __shared__ __align__(16) u16 smem[2 * BUFU];

    int tid = threadIdx.x, lane = tid & 63, wv = tid >> 6;
    int fr = lane & 15, fq = lane >> 4;
    int wm = wv >> 1, wn = wv & 1;

    int fid = blockIdx.x;
    int xcd = fid & 7, w = fid >> 3;
    int slab = w / nb, n = w - slab * nb;    // n-inner within each XCD slab
    int mtile = slab * 8 + xcd;
    if (mtile >= mtiles) return;
    int m0 = mtile * (MBL * 16), n0 = n * (NBL * 16);

    int Kf = K >> 5;
    size_t tstr = (size_t)Kf * 512;

    // staging pointers: blob bi = wv + i*4; [0,MBL)=A-blobs, rest B-blobs
    const u16* gp[NST];
    u16* ldst[NST];
    #pragma unroll
    for (int i = 0; i < NST; ++i) {
        int bi = wv + i * 4;
        gp[i] = (bi < MBL)
            ? Ab + ((size_t)(m0 >> 4) + bi) * tstr + lane * 8
            : Bb + ((size_t)(n0 >> 4) + (bi - MBL)) * tstr + lane * 8;
        ldst[i] = smem + bi * 512;
    }

    f32x4 acc[MH2][NW2];
    #pragma unroll
    for (int mi = 0; mi < MH2; ++mi)
        #pragma unroll
        for (int ni = 0; ni < NW2; ++ni) acc[mi][ni] = (f32x4){0.f, 0.f, 0.f, 0.f};

    #pragma unroll
    for (int i = 0; i < NST; ++i) load_lds16(gp[i], ldst[i]);
    __syncthreads();

    for (int t = 0; t < Kf; ++t) {
        int cur = (t & 1) * BUFU, nxt = ((t + 1) & 1) * BUFU;
        if (t + 1 < Kf) {
            #pragma unroll
            for (int i = 0; i < NST; ++i)
                load_lds16(gp[i] + (size_t)(t + 1) * 512, ldst[i] + nxt);
        }
        bf16x8 a[MH2], bfr[NW2];
        #pragma unroll
        for (int mi = 0; mi < MH2; ++mi)
            a[mi] = *(const bf16x8*)(smem + cur + (wm * MH2 + mi) * 512 + lane * 8);
        #pragma unroll
        for (int ni = 0; ni < NW2; ++ni)
            bfr[ni] = *(const bf16x8*)(smem + cur + (MBL + wn * NW2 + ni) * 512 + lane * 8);
        #pragma unroll
        for (int mi = 0; mi < MH2; ++mi)
            #pragma unroll
            for (int ni = 0; ni < NW2; ++ni)
                acc[mi][ni] = __builtin_amdgcn_mfma_f32_16x16x32_bf16(
                    a[mi], bfr[ni], acc[mi][ni], 0, 0, 0);
        __syncthreads();
    }

    int m0w = m0 + wm * (MH2 * 16);
    int n0w = n0 + wn * (NW2 * 16);
    float* outf = (float*)outv;
    u16* outblob = (u16*)outv;

    if constexpr ((FLAGS & 8) != 0) {
        // qkv scatter: wave's 64-col span is one (sec, head), uniform per wave
        int sec = n0w / CDIM;
        int h   = (n0w % CDIM) / 64;
        #pragma unroll
        for (int mi = 0; mi < MH2; ++mi) {
            #pragma unroll
            for (int rg = 0; rg < 4; ++rg) {
                int gm = m0w + mi * 16 + fq * 4 + rg;
                if (gm >= M) continue;
                int b   = gm / NTOK;
                int row = gm - b * NTOK;
                int bh  = b * NH + h;
                #pragma unroll
                for (int ni = 0; ni < NW2; ++ni) {
                    int d = ni * 16 + fr;
                    float v = acc[mi][ni][rg] + bias[n0w + d];
                    __hip_bfloat16 hb = __float2bfloat16(v);
                    if (sec == 0) {
                        Qp[(size_t)(bh * QT + (row >> 4)) * 1024 + (d >> 5) * 512 +
                           (((d >> 3) & 3) * 16 + (row & 15)) * 8 + (d & 7)] = *(u16*)&hb;
                    } else if (sec == 1) {
                        Kp[(size_t)(bh * QT + (row >> 4)) * 1024 + (d >> 5) * 512 +
                           (((d >> 3) & 3) * 16 + (row & 15)) * 8 + (d & 7)] = *(u16*)&hb;
                    } else {
                        Vp[((size_t)(bh * 4 + (d >> 4)) * 20 + (row >> 5)) * 512 +
                           (((row >> 3) & 3) * 16 + (d & 15)) * 8 + (row & 7)] = *(u16*)&hb;
                    }
                }
            }
        }
        return;
    }

    if constexpr ((FLAGS & 4) != 0) {
        // blob out: per-wave private 2KB LDS staging per m-blob (wave-sync:
        // same wave writes then reads, program order), then linear 16B stores.
        u16* sb = smem + wv * 1024;
        int KfO = Nc >> 5;
        #pragma unroll
        for (int mi = 0; mi < MH2; ++mi) {
            #pragma unroll
            for (int ni = 0; ni < NW2; ++ni)
                #pragma unroll
                for (int rg = 0; rg < 4; ++rg) {
                    int cl = ni * 16 + fr;
                    float v = acc[mi][ni][rg] + bias[n0w + cl];
                    if (FLAGS & 1) v = fast_gelu(v);
                    __hip_bfloat16 hb = __float2bfloat16(v);
                    sb[(cl >> 5) * 512 +
                       (((cl >> 3) & 3) * 16 + fq * 4 + rg) * 8 + (cl & 7)] = *(u16*)&hb;
                }
            u16* dst = outblob + ((size_t)((m0w >> 4) + mi) * KfO + (n0w >> 5)) * 512;
            *(bf16x8*)(dst + lane * 16)     = *(const bf16x8*)(sb + lane * 16);
            *(bf16x8*)(dst + lane * 16 + 8) = *(const bf16x8*)(sb + lane * 16 + 8);
        }
        return;
    }

    #pragma unroll
    for (int mi = 0; mi < MH2; ++mi) {
        #pragma unroll
        for (int rg = 0; rg < 4; ++rg) {
            int gm = m0w + mi * 16 + fq * 4 + rg;
            if (gm >= M) continue;
            #pragma unroll
            for (int ni = 0; ni < NW2; ++ni) {
                int gn = n0w + ni * 16 + fr;
                float v = acc[mi][ni][rg] + bias[gn];
                if (res) v += res[(size_t)gm * Nc + gn];
                outf[(size_t)gm * Nc + gn] = v;
            }
        }
    }
}

// ---------------------------------------------------------------------------
// MFMA flash attention, SWAPPED QK^T (in-register softmax rows).
// sc[nt] = mfma(K_frag, Q_frag) = S^T: col = lane&15 = q, row = fq*4+rg = key.
// Works with ZERO storage change: the blob packing is simultaneously the
// A-operand layout for (m,c) and the B-operand layout for (n,k).
// Each lane owns q = fr's full 16 key-scores per step -> row max/sum are
// in-register trees + 2 shfl_xor (off 16/32) instead of 4x4 butterflies
// (32 -> 8 DS-shuffles per step). P-write: 4x ds_write_b64 packed quads.
// PV unchanged (psw layout identical). alpha/l broadcast to O's q-rows
// (q = fq*4+rg) via 4 bpermutes.
// XCD-swizzled grid (R5), double-buffered K/V staging, setprio on MFMA.
// ---------------------------------------------------------------------------
__global__ __launch_bounds__(256) void attn_mfma(
    const u16* __restrict__ Qp, const u16* __restrict__ Kp,
    const u16* __restrict__ Vp, u16* __restrict__ outp)
{
    __shared__ __align__(16) u16 Ks[2][4096];
    __shared__ __align__(16) u16 Vs[2][4096];
    __shared__ __align__(16) u16 Ps[4 * 16 * 72];

    int fid = blockIdx.x;
    int xcd = fid & 7, w = fid >> 3;       // w in [0, 240)
    int bhl = w / 10, qc = w - bhl * 10;   // qc-inner
    int bh = xcd * 24 + bhl;
    int b = bh / NH, h = bh % NH;
    int t = threadIdx.x, lane = t & 63, wv = t >> 6;
    int fr = lane & 15, fq = lane >> 4;

    int mt = qc * 4 + wv;
    const u16* qbase = Qp + (size_t)(bh * QT + mt) * 1024 + lane * 8;
    bf16x8 qf0 = *(const bf16x8*)(qbase);
    bf16x8 qf1 = *(const bf16x8*)(qbase + 512);

    const u16* kg = Kp + (size_t)bh * (QT * 1024) + wv * 1024 + lane * 8;
    const u16* vg = Vp + ((size_t)(bh * 4 + wv) * 20) * 512 + lane * 8;
    u16* psw = Ps + wv * (16 * 72);

#define STAGE(buf, kt) do {                                        \
    load_lds16(kg + (kt) * 4096,       &Ks[buf][wv * 1024]);       \
    load_lds16(kg + (kt) * 4096 + 512, &Ks[buf][wv * 1024 + 512]); \
    load_lds16(vg + (kt) * 1024,       &Vs[buf][wv * 1024]);       \
    load_lds16(vg + (kt) * 1024 + 512, &Vs[buf][wv * 1024 + 512]); \
} while (0)

    f32x4 o[4];
    #pragma unroll
    for (int i = 0; i < 4; ++i) o[i] = (f32x4){0.f, 0.f, 0.f, 0.f};
    float m_r = -1e30f, l_r = 0.f;   // per-lane state for q = fr

    STAGE(0, 0);
    __syncthreads();

    for (int kt = 0; kt < 10; ++kt) {
        int cur = kt & 1;
        if (kt + 1 < 10) STAGE(cur ^ 1, kt + 1);

        f32x4 sc[4];
        __builtin_amdgcn_s_setprio(1);
        #pragma unroll
        for (int nt = 0; nt < 4; ++nt) {
            sc[nt] = (f32x4){0.f, 0.f, 0.f, 0.f};
            bf16x8 kf0 = *(const bf16x8*)(&Ks[cur][(nt * 2 + 0) * 512] + lane * 8);
            bf16x8 kf1 = *(const bf16x8*)(&Ks[cur][(nt * 2 + 1) * 512] + lane * 8);
            // SWAPPED: A = K (keys = rows), B = Q (q = cols) -> S^T
            sc[nt] = __builtin_amdgcn_mfma_f32_16x16x32_bf16(kf0, qf0, sc[nt], 0, 0, 0);
            sc[nt] = __builtin_amdgcn_mfma_f32_16x16x32_bf16(kf1, qf1, sc[nt], 0, 0, 0);
        }
        __builtin_amdgcn_s_setprio(0);

        int j0 = kt * 64;
        float p[4][4];
        #pragma unroll
        for (int nt = 0; nt < 4; ++nt)
            #pragma unroll
            for (int rg = 0; rg < 4; ++rg) {
                int k = j0 + nt * 16 + fq * 4 + rg;
                p[nt][rg] = (k < NTOK) ? sc[nt][rg] * 0.125f : -1e30f;
            }
        // in-register max tree over the lane's 16 scores
        float mx01 = fmaxf(fmaxf(p[0][0], p[0][1]), fmaxf(p[0][2], p[0][3]));
        float mx23 = fmaxf(fmaxf(p[1][0], p[1][1]), fmaxf(p[1][2], p[1][3]));
        float mx45 = fmaxf(fmaxf(p[2][0], p[2][1]), fmaxf(p[2][2], p[2][3]));
        float mx67 = fmaxf(fmaxf(p[3][0], p[3][1]), fmaxf(p[3][2], p[3][3]));
        float pm = fmaxf(fmaxf(mx01, mx23), fmaxf(mx45, mx67));
        // combine the 4 fq replicas of this q (lanes fr, fr+16, fr+32, fr+48)
        pm = fmaxf(pm, __shfl_xor(pm, 16));
        pm = fmaxf(pm, __shfl_xor(pm, 32));

        float mn = fmaxf(m_r, pm);
        float alpha = __expf(m_r - mn);
        m_r = mn;

        float rs = 0.f;
        #pragma unroll
        for (int nt = 0; nt < 4; ++nt)
            #pragma unroll
            for (int rg = 0; rg < 4; ++rg) {
                float pv = __expf(p[nt][rg] - mn);
                p[nt][rg] = pv;
                rs += pv;
            }
        rs += __shfl_xor(rs, 16);
        rs += __shfl_xor(rs, 32);
        l_r = l_r * alpha + rs;

        // P -> psw: lane owns row q=fr, 4 consecutive keys per nt -> b64 store
        #pragma unroll
        for (int nt = 0; nt < 4; ++nt) {
            __hip_bfloat16 c0 = __float2bfloat16(p[nt][0]);
            __hip_bfloat16 c1 = __float2bfloat16(p[nt][1]);
            __hip_bfloat16 c2 = __float2bfloat16(p[nt][2]);
            __hip_bfloat16 c3 = __float2bfloat16(p[nt][3]);
            ushort4 pk = make_ushort4(*(u16*)&c0, *(u16*)&c1, *(u16*)&c2, *(u16*)&c3);
            *(ushort4*)(psw + fr * 72 + nt * 16 + fq * 4) = pk;
        }

        // rescale O: its rows are q = fq*4+rg -> fetch those lanes' alpha
        #pragma unroll
        for (int rg = 0; rg < 4; ++rg) {
            float al = __shfl(alpha, fq * 4 + rg);
            #pragma unroll
            for (int dt = 0; dt < 4; ++dt)
                o[dt][rg] *= al;
        }

        bf16x8 pf0 = *(const bf16x8*)(psw + fr * 72 + fq * 8);
        bf16x8 pf1 = *(const bf16x8*)(psw + fr * 72 + 32 + fq * 8);
        __builtin_amdgcn_s_setprio(1);
        #pragma unroll
        for (int dt = 0; dt < 4; ++dt) {
            bf16x8 bv0 = *(const bf16x8*)(&Vs[cur][(dt * 2 + 0) * 512] + lane * 8);
            bf16x8 bv1 = *(const bf16x8*)(&Vs[cur][(dt * 2 + 1) * 512] + lane * 8);
            o[dt] = __builtin_amdgcn_mfma_f32_16x16x32_bf16(pf0, bv0, o[dt], 0, 0, 0);
            o[dt] = __builtin_amdgcn_mfma_f32_16x16x32_bf16(pf1, bv1, o[dt], 0, 0, 0);
        }
        __builtin_amdgcn_s_setprio(0);
        __syncthreads();   // drains this step's prefetch + read-sync of cur
    }
#undef STAGE

    #pragma unroll
    for (int rg = 0; rg < 4; ++rg) {
        int row = qc * 64 + wv * 16 + fq * 4 + rg;
        if (row < NTOK) {
            float lq = __shfl(l_r, fq * 4 + rg);   // l for O's q-row
            float rl = 1.0f / lq;
            int grow = b * NTOK + row;
            #pragma unroll
            for (int dt = 0; dt < 4; ++dt) {
                __hip_bfloat16 hb = __float2bfloat16(o[dt][rg] * rl);
                outp[blobA(grow, h * 64 + dt * 16 + fr, KF_C)] = *(u16*)&hb;
            }
        }
    }
}

// ---------------------------------------------------------------------------
static inline int tg_grid(int nb, int mt) { return 8 * nb * ((mt + 7) / 8); }

extern "C" void kernel_launch(void* const* d_in, const int* in_sizes, int n_in,
                              void* d_out, int out_size, void* d_ws, size_t ws_size,
                              hipStream_t stream)
{
    const float* x      = (const float*)d_in[0];
    const float* ln1_g  = (const float*)d_in[1];
    const float* ln1_b  = (const float*)d_in[2];
    const float* w_qkv  = (const float*)d_in[3];
    const float* b_qkv  = (const float*)d_in[4];
    const float* w_proj = (const float*)d_in[5];
    const float* b_proj = (const float*)d_in[6];
    const float* ln2_g  = (const float*)d_in[7];
    const float* ln2_b  = (const float*)d_in[8];
    const float* w_fc1  = (const float*)d_in[9];
    const float* b_fc1  = (const float*)d_in[10];
    const float* w_fc2  = (const float*)d_in[11];
    const float* b_fc2  = (const float*)d_in[12];
    float* out = (float*)d_out;

    char* w = (char*)d_ws;
    u16* Bqkv = (u16*)w; w += (size_t)3*CDIM*CDIM*2;
    u16* Bproj= (u16*)w; w += (size_t)CDIM*CDIM*2;
    u16* Bfc1 = (u16*)w; w += (size_t)HID*CDIM*2;
    u16* Bfc2 = (u16*)w; w += (size_t)CDIM*HID*2;
    u16* hA   = (u16*)w; w += (size_t)RPAD*CDIM*2;   // blob activations (768)
    u16* h3A  = (u16*)w; w += (size_t)RPAD*HID*2;    // blob activations (3072)
    u16* Qp   = (u16*)w; w += (size_t)BH*QT*1024*2;
    u16* Kp   = (u16*)w; w += (size_t)BH*QT*1024*2;
    u16* Vp   = (u16*)w; w += (size_t)BH*4*20*512*2;

    int mt128 = (RTOT + 127) / 128;   // 73  (73*128 = 9344 = RPAD: reads in-bounds)
    int mt64  = (RTOT + 63) / 64;     // 145

    // 0. weights -> fragment blobs
    wconvert_blob<<<dim3(3*CDIM/256, CDIM/8), 256, 0, stream>>>(w_qkv,  Bqkv, CDIM, 3*CDIM);
    wconvert_blob<<<dim3(CDIM/256,   CDIM/8), 256, 0, stream>>>(w_proj, Bproj, CDIM, CDIM);
    wconvert_blob<<<dim3(HID/256,    CDIM/8), 256, 0, stream>>>(w_fc1,  Bfc1, CDIM, HID);
    wconvert_blob<<<dim3(CDIM/256,   HID/8),  256, 0, stream>>>(w_fc2,  Bfc2, HID, CDIM);

    // 1. hA = LN1(x)  (blob)
    ln_kernel<<<RTOT, 256, 0, stream>>>(x, ln1_g, ln1_b, hA);
    // 2. qkv GEMM -> Q/K/V blobs  (128x128 tiles, swizzled 18x73)
    tile_gemm<8, 8, 8><<<tg_grid(3*CDIM/128, mt128), 256, 0, stream>>>(
        hA, Bqkv, b_qkv, nullptr, nullptr, Qp, Kp, Vp,
        RTOT, 3*CDIM, CDIM, 3*CDIM/128, mt128);
    // 3. attention -> hA (blob)
    attn_mfma<<<8 * 24 * 10, 256, 0, stream>>>(Qp, Kp, Vp, hA);
    // 4. x1 = x + hA @ Bproj^T + b_proj -> d_out (fp32; 64x128, swizzled 6x145)
    tile_gemm<4, 8, 0><<<tg_grid(CDIM/128, mt64), 256, 0, stream>>>(
        hA, Bproj, b_proj, x, out, nullptr, nullptr, nullptr,
        RTOT, CDIM, CDIM, CDIM/128, mt64);
    // 5. hA = LN2(x1)  (blob)
    ln_kernel<<<RTOT, 256, 0, stream>>>(out, ln2_g, ln2_b, hA);
    // 6. h3A = gelu(hA @ Bfc1^T + b_fc1)  (blob out; 128x128, swizzled 24x73)
    tile_gemm<8, 8, 5><<<tg_grid(HID/128, mt128), 256, 0, stream>>>(
        hA, Bfc1, b_fc1, nullptr, h3A, nullptr, nullptr, nullptr,
        RTOT, HID, CDIM, HID/128, mt128);
    // 7. out = x1 + h3A @ Bfc2^T + b_fc2  (fp32; 64x128, swizzled 6x145)
    tile_gemm<4, 8, 0><<<tg_grid(CDIM/128, mt64), 256, 0, stream>>>(
        h3A, Bfc2, b_fc2, out, out, nullptr, nullptr, nullptr,
        RTOT, CDIM, HID, CDIM/128, mt64);
}